// Round 1
// baseline (1216.761 us; speedup 1.0000x reference)
//
#include <hip/hip_runtime.h>
#include <stdint.h>

// Problem constants (fixed by reference)
#define D_MODEL   768
#define D_INNER   1536
#define D_STATE   16
#define DT_RANK   48
#define NB        4
#define TSEQ      1024
#define NTOK      4096         // NB*TSEQ
#define EPS       1e-5f
#define CHUNK     32           // scan chunk length
#define NCHUNK    32           // TSEQ/CHUNK
#define XP_KSEG   8            // split-K segments for x_proj
#define XP_PAD    36           // padded LDS stride (floats) for x_proj tiles

typedef __bf16 bf16;
typedef __bf16 bf16x8 __attribute__((ext_vector_type(8)));
typedef float  floatx4 __attribute__((ext_vector_type(4)));

__device__ __forceinline__ float silu_f(float v)     { return v / (1.f + __expf(-v)); }
__device__ __forceinline__ float softplus_f(float v) { return v > 20.f ? v : __logf(1.f + __expf(v)); }

// async global->LDS, 16B per lane; LDS dest is wave-uniform base + lane*16
__device__ __forceinline__ void async_ld16(const void* g, void* l) {
  __builtin_amdgcn_global_load_lds((__attribute__((address_space(1))) uint32_t*)g,
                                   (__attribute__((address_space(3))) uint32_t*)l, 16, 0, 0);
}

// ---------------------------------------------------------------- prep: fp32 -> bf16 weights
__global__ __launch_bounds__(256) void prep_k(const float* __restrict__ win, const float* __restrict__ wout,
                                              bf16* __restrict__ bin, bf16* __restrict__ bout) {
  const int i = blockIdx.x * 256 + threadIdx.x;     // grid covers exactly NIN+NOUT
  const int NIN = 4 * 3072 * 768;
  if (i < NIN) bin[i] = (bf16)win[i];
  else         bout[i - NIN] = (bf16)wout[i - NIN];
}

// ---------------------------------------------------------------- input projection (K=12)
__global__ __launch_bounds__(256) void input_proj_k(const float* __restrict__ x, const float* __restrict__ w,
                                                    const float* __restrict__ bvec, float* __restrict__ h) {
  const int idx = blockIdx.x * 256 + threadIdx.x;   // NTOK*768
  const int d = idx % D_MODEL;
  const int t = idx / D_MODEL;
  float acc = bvec[d];
  #pragma unroll
  for (int f = 0; f < 12; ++f) acc = fmaf(x[t * 12 + f], w[d * 12 + f], acc);
  h[idx] = acc;
}

// ---------------------------------------------------------------- rmsnorm -> bf16
__global__ __launch_bounds__(256) void rmsnorm_k(const float* __restrict__ h, const float* __restrict__ lnw,
                                                 bf16* __restrict__ xn) {
  const int t = blockIdx.x;
  const float* __restrict__ hr = h + (size_t)t * D_MODEL;
  float v[3];
  float ss = 0.f;
  #pragma unroll
  for (int i = 0; i < 3; ++i) { v[i] = hr[threadIdx.x + i * 256]; ss = fmaf(v[i], v[i], ss); }
  #pragma unroll
  for (int o = 32; o > 0; o >>= 1) ss += __shfl_down(ss, o, 64);
  __shared__ float red[4];
  if ((threadIdx.x & 63) == 0) red[threadIdx.x >> 6] = ss;
  __syncthreads();
  const float tot = red[0] + red[1] + red[2] + red[3];
  const float rs = rsqrtf(tot / (float)D_MODEL + EPS);
  #pragma unroll
  for (int i = 0; i < 3; ++i) {
    const int d = threadIdx.x + i * 256;
    xn[(size_t)t * D_MODEL + d] = (bf16)(v[i] * rs * lnw[d]);
  }
}

// ---------------------------------------------------------------- bf16 MFMA GEMM: C[4096,N] = A[4096,K] @ B[N,K]^T
// m97 structure: 128x128 tile, BK=32, 4 waves of 64x64, global_load_lds width16.
template <bool ADD>
__global__ __launch_bounds__(256) void gemm_bt(const bf16* __restrict__ A, const bf16* __restrict__ B,
                                               float* __restrict__ C, const int N, const int K) {
  alignas(16) __shared__ bf16 As[128 * 32];
  alignas(16) __shared__ bf16 Bs[128 * 32];
  const int tid = threadIdx.x;
  const int lane = tid & 63;
  const int wid = tid >> 6;
  const int wm = wid & 1, wn = wid >> 1;
  const int m0 = blockIdx.x * 128, n0 = blockIdx.y * 128;

  floatx4 acc[4][4];
  #pragma unroll
  for (int i = 0; i < 4; ++i)
    #pragma unroll
    for (int j = 0; j < 4; ++j) acc[i][j] = (floatx4){0.f, 0.f, 0.f, 0.f};

  const int srow = lane >> 2;          // staging: row within 16-row segment
  const int skp  = (lane & 3) * 8;     // staging: k offset (8 bf16 = 16B)
  const int fr = lane & 15;            // fragment row
  const int fk = (lane >> 4) * 8;      // fragment k

  for (int k0 = 0; k0 < K; k0 += 32) {
    __syncthreads();                   // all waves done reading LDS from prev iter
    #pragma unroll
    for (int i = 0; i < 2; ++i) {
      const int seg = wid * 2 + i;     // 8 segments x 1KB per matrix
      const int row = seg * 16 + srow;
      async_ld16(A + (size_t)(m0 + row) * K + k0 + skp, (char*)As + seg * 1024);
      async_ld16(B + (size_t)(n0 + row) * K + k0 + skp, (char*)Bs + seg * 1024);
    }
    __syncthreads();                   // compiler drains vmcnt(0) before barrier
    bf16x8 a[4], b[4];
    #pragma unroll
    for (int t = 0; t < 4; ++t) {
      a[t] = *(const bf16x8*)&As[(wm * 64 + t * 16 + fr) * 32 + fk];
      b[t] = *(const bf16x8*)&Bs[(wn * 64 + t * 16 + fr) * 32 + fk];
    }
    #pragma unroll
    for (int i = 0; i < 4; ++i)
      #pragma unroll
      for (int j = 0; j < 4; ++j)
        acc[i][j] = __builtin_amdgcn_mfma_f32_16x16x32_bf16(a[i], b[j], acc[i][j], 0, 0, 0);
  }

  const int quad = lane >> 4, col = lane & 15;
  #pragma unroll
  for (int i = 0; i < 4; ++i)
    #pragma unroll
    for (int j = 0; j < 4; ++j) {
      const int gm0 = m0 + wm * 64 + i * 16 + quad * 4;
      const int gn  = n0 + wn * 64 + j * 16 + col;
      #pragma unroll
      for (int r = 0; r < 4; ++r) {
        const size_t off = (size_t)(gm0 + r) * N + gn;
        const float v = acc[i][j][r];
        C[off] = ADD ? (C[off] + v) : v;
      }
    }
}

// ---------------------------------------------------------------- causal depthwise conv4 + silu
__global__ __launch_bounds__(256) void conv_silu_k(const float* __restrict__ xz, const float* __restrict__ cw,
                                                   const float* __restrict__ cb, float* __restrict__ xx) {
  const int idx = blockIdx.x * 256 + threadIdx.x;   // NTOK*1536
  const int d = idx % D_INNER;
  const int bt = idx / D_INNER;
  const int t = bt & (TSEQ - 1);
  float acc = cb[d];
  #pragma unroll
  for (int j = 0; j < 4; ++j) {
    const int tt = t - 3 + j;
    if (tt >= 0) acc = fmaf(xz[(size_t)(bt - 3 + j) * (2 * D_INNER) + d], cw[d * 4 + j], acc);
  }
  xx[idx] = silu_f(acc);
}

// ---------------------------------------------------------------- x_proj (N=80, split-K fp32, LDS tiled)
__global__ __launch_bounds__(256) void xproj_k(const float* __restrict__ xx, const float* __restrict__ xpw,
                                               float* __restrict__ dbcp) {
  alignas(16) __shared__ float xs[64 * XP_PAD];
  alignas(16) __shared__ float wsd[80 * XP_PAD];
  const int tid = threadIdx.x;
  const int m0 = blockIdx.x * 64;
  const int kbase = blockIdx.y * (D_INNER / XP_KSEG);   // 192 per segment
  const int mg = tid & 15, ng = tid >> 4;               // 4 tokens x 5 outputs per thread
  float acc[4][5];
  #pragma unroll
  for (int i = 0; i < 4; ++i)
    #pragma unroll
    for (int j = 0; j < 5; ++j) acc[i][j] = 0.f;

  for (int k0 = 0; k0 < D_INNER / XP_KSEG; k0 += 32) {
    __syncthreads();
    #pragma unroll
    for (int i = 0; i < 2; ++i) {                       // 64x32 activation tile
      const int li = tid + i * 256;
      const int row = li >> 3, c4 = (li & 7) * 4;
      *(float4*)&xs[row * XP_PAD + c4] = *(const float4*)&xx[(size_t)(m0 + row) * D_INNER + kbase + k0 + c4];
    }
    #pragma unroll
    for (int i = 0; i < 3; ++i) {                       // 80x32 weight tile
      const int li = tid + i * 256;
      if (li < 640) {
        const int row = li >> 3, c4 = (li & 7) * 4;
        *(float4*)&wsd[row * XP_PAD + c4] = *(const float4*)&xpw[(size_t)row * D_INNER + kbase + k0 + c4];
      }
    }
    __syncthreads();
    #pragma unroll
    for (int q = 0; q < 8; ++q) {
      float4 wv[5];
      #pragma unroll
      for (int j = 0; j < 5; ++j) wv[j] = *(const float4*)&wsd[(ng * 5 + j) * XP_PAD + q * 4];
      #pragma unroll
      for (int i = 0; i < 4; ++i) {
        const float4 xv = *(const float4*)&xs[(mg * 4 + i) * XP_PAD + q * 4];
        #pragma unroll
        for (int j = 0; j < 5; ++j) {
          acc[i][j] = fmaf(xv.x, wv[j].x, acc[i][j]);
          acc[i][j] = fmaf(xv.y, wv[j].y, acc[i][j]);
          acc[i][j] = fmaf(xv.z, wv[j].z, acc[i][j]);
          acc[i][j] = fmaf(xv.w, wv[j].w, acc[i][j]);
        }
      }
    }
  }
  #pragma unroll
  for (int i = 0; i < 4; ++i)
    #pragma unroll
    for (int j = 0; j < 5; ++j)
      dbcp[((size_t)blockIdx.y * NTOK + m0 + mg * 4 + i) * 80 + ng * 5 + j] = acc[i][j];
}

__global__ __launch_bounds__(256) void reduce_dbc_k(const float* __restrict__ dbcp, float* __restrict__ dbc) {
  const int idx = blockIdx.x * 256 + threadIdx.x;       // NTOK*80
  float s = 0.f;
  #pragma unroll
  for (int k = 0; k < XP_KSEG; ++k) s += dbcp[(size_t)k * NTOK * 80 + idx];
  dbc[idx] = s;
}

// ---------------------------------------------------------------- dt_proj + softplus (K=48 in registers)
__global__ __launch_bounds__(256) void dtproj_k(const float* __restrict__ dbc, const float* __restrict__ dtw,
                                                const float* __restrict__ dtb, float* __restrict__ delta) {
  const int d = blockIdx.y * 256 + threadIdx.x;
  const int t0 = blockIdx.x * 16;
  float w[DT_RANK];
  #pragma unroll
  for (int k = 0; k < DT_RANK; k += 4) {
    const float4 t4 = *(const float4*)&dtw[(size_t)d * DT_RANK + k];
    w[k] = t4.x; w[k + 1] = t4.y; w[k + 2] = t4.z; w[k + 3] = t4.w;
  }
  const float bias = dtb[d];
  for (int m = 0; m < 16; ++m) {
    const float* __restrict__ db = dbc + (size_t)(t0 + m) * 80;   // lane-uniform -> s_load
    float acc = bias;
    #pragma unroll
    for (int k = 0; k < DT_RANK; ++k) acc = fmaf(db[k], w[k], acc);
    delta[(size_t)(t0 + m) * D_INNER + d] = softplus_f(acc);
  }
}

// ---------------------------------------------------------------- chunked selective scan, phase 1:
// per chunk: P[n] = prod a_t[n], S[n] = local state from zero init
__global__ __launch_bounds__(256) void scan_p1_k(const float* __restrict__ delta, const float* __restrict__ xx,
                                                 const float* __restrict__ dbc, const float* __restrict__ Alog,
                                                 float* __restrict__ P, float* __restrict__ S) {
  const int c = blockIdx.x;
  const int d = blockIdx.y * 256 + threadIdx.x;
  const int b = blockIdx.z;
  float A[16], Sv[16], Pv[16];
  #pragma unroll
  for (int n = 0; n < 16; ++n) {
    A[n] = -__expf(Alog[(size_t)d * 16 + n]);
    Sv[n] = 0.f; Pv[n] = 1.f;
  }
  const int bt0 = b * TSEQ + c * CHUNK;
  for (int tt = 0; tt < CHUNK; ++tt) {
    const size_t bt = bt0 + tt;
    const float du  = delta[bt * D_INNER + d];
    const float xv  = xx[bt * D_INNER + d];
    const float dux = du * xv;
    const float* __restrict__ Bp = dbc + bt * 80 + DT_RANK;       // lane-uniform -> s_load
    #pragma unroll
    for (int n = 0; n < 16; ++n) {
      const float e = __expf(du * A[n]);
      Sv[n] = fmaf(e, Sv[n], dux * Bp[n]);
      Pv[n] *= e;
    }
  }
  const size_t base = ((size_t)(b * NCHUNK + c) * 16) * D_INNER + d;
  #pragma unroll
  for (int n = 0; n < 16; ++n) {
    P[base + (size_t)n * D_INNER] = Pv[n];
    S[base + (size_t)n * D_INNER] = Sv[n];
  }
}

// phase 2+3: fold chunk prefix (diagonal combine), replay chunk, fuse D-skip + silu(z) gate, emit bf16
__global__ __launch_bounds__(256) void scan_p3_k(const float* __restrict__ delta, const float* __restrict__ xx,
                                                 const float* __restrict__ dbc, const float* __restrict__ Alog,
                                                 const float* __restrict__ P, const float* __restrict__ S,
                                                 const float* __restrict__ xz, const float* __restrict__ Dsk,
                                                 bf16* __restrict__ yg) {
  const int c = blockIdx.x;
  const int d = blockIdx.y * 256 + threadIdx.x;
  const int b = blockIdx.z;
  float A[16], H[16];
  #pragma unroll
  for (int n = 0; n < 16; ++n) { A[n] = -__expf(Alog[(size_t)d * 16 + n]); H[n] = 0.f; }
  for (int cc = 0; cc < c; ++cc) {
    const size_t pb = ((size_t)(b * NCHUNK + cc) * 16) * D_INNER + d;
    #pragma unroll
    for (int n = 0; n < 16; ++n)
      H[n] = fmaf(P[pb + (size_t)n * D_INNER], H[n], S[pb + (size_t)n * D_INNER]);
  }
  const float dsk = Dsk[d];
  const int bt0 = b * TSEQ + c * CHUNK;
  for (int tt = 0; tt < CHUNK; ++tt) {
    const size_t bt = bt0 + tt;
    const float du  = delta[bt * D_INNER + d];
    const float xv  = xx[bt * D_INNER + d];
    const float dux = du * xv;
    const float* __restrict__ Bp = dbc + bt * 80 + DT_RANK;
    const float* __restrict__ Cp = Bp + 16;
    float y = 0.f;
    #pragma unroll
    for (int n = 0; n < 16; ++n) {
      const float e = __expf(du * A[n]);
      H[n] = fmaf(e, H[n], dux * Bp[n]);
      y = fmaf(H[n], Cp[n], y);
    }
    const float z = xz[bt * (2 * D_INNER) + D_INNER + d];
    yg[bt * D_INNER + d] = (bf16)((y + dsk * xv) * silu_f(z));
  }
}

// ---------------------------------------------------------------- final rmsnorm + head dot
__global__ __launch_bounds__(256) void final_k(const float* __restrict__ h, const float* __restrict__ nw,
                                               const float* __restrict__ hw, const float* __restrict__ hb,
                                               float* __restrict__ out) {
  const int t = blockIdx.x;
  const float* __restrict__ hr = h + (size_t)t * D_MODEL;
  float ss = 0.f, dt_ = 0.f;
  #pragma unroll
  for (int i = 0; i < 3; ++i) {
    const int d = threadIdx.x + i * 256;
    const float v = hr[d];
    ss  = fmaf(v, v, ss);
    dt_ = fmaf(v, nw[d] * hw[d], dt_);
  }
  #pragma unroll
  for (int o = 32; o > 0; o >>= 1) { ss += __shfl_down(ss, o, 64); dt_ += __shfl_down(dt_, o, 64); }
  __shared__ float r0[4], r1[4];
  if ((threadIdx.x & 63) == 0) { r0[threadIdx.x >> 6] = ss; r1[threadIdx.x >> 6] = dt_; }
  __syncthreads();
  if (threadIdx.x == 0) {
    const float sst = r0[0] + r0[1] + r0[2] + r0[3];
    const float dtt = r1[0] + r1[1] + r1[2] + r1[3];
    out[t] = dtt * rsqrtf(sst / (float)D_MODEL + EPS) + hb[0];
  }
}

// ---------------------------------------------------------------- host orchestration
extern "C" void kernel_launch(void* const* d_in, const int* in_sizes, int n_in,
                              void* d_out, int out_size, void* d_ws, size_t ws_size,
                              hipStream_t stream) {
  (void)in_sizes; (void)n_in; (void)out_size; (void)ws_size;
  const float* x     = (const float*)d_in[0];
  const float* inpw  = (const float*)d_in[1];
  const float* inpb  = (const float*)d_in[2];
  const float* inprj = (const float*)d_in[3];
  const float* convw = (const float*)d_in[4];
  const float* convb = (const float*)d_in[5];
  const float* xprjw = (const float*)d_in[6];
  const float* dtw   = (const float*)d_in[7];
  const float* dtb   = (const float*)d_in[8];
  const float* alog  = (const float*)d_in[9];
  const float* dskip = (const float*)d_in[10];
  const float* outw  = (const float*)d_in[11];
  const float* lnw   = (const float*)d_in[12];
  const float* normw = (const float*)d_in[13];
  const float* headw = (const float*)d_in[14];
  const float* headb = (const float*)d_in[15];
  float* out = (float*)d_out;

  // workspace layout (~198 MB total)
  char* p = (char*)d_ws;
  auto take = [&](size_t bytes) { char* q = p; p += (bytes + 255) & ~(size_t)255; return q; };
  bf16*  wbin  = (bf16*) take((size_t)4 * 3072 * 768 * 2);
  bf16*  wbout = (bf16*) take((size_t)4 * 768 * 1536 * 2);
  float* h     = (float*)take((size_t)NTOK * D_MODEL * 4);
  bf16*  xn    = (bf16*) take((size_t)NTOK * D_MODEL * 2);
  float* xz    = (float*)take((size_t)NTOK * 2 * D_INNER * 4);
  float* xxa   = (float*)take((size_t)NTOK * D_INNER * 4);
  float* dbcp  = (float*)take((size_t)XP_KSEG * NTOK * 80 * 4);
  float* dbc   = (float*)take((size_t)NTOK * 80 * 4);
  float* dlt   = (float*)take((size_t)NTOK * D_INNER * 4);
  float* Pb    = (float*)take((size_t)NB * NCHUNK * 16 * D_INNER * 4);
  float* Sb    = (float*)take((size_t)NB * NCHUNK * 16 * D_INNER * 4);
  bf16*  yg    = (bf16*) take((size_t)NTOK * D_INNER * 2);

  prep_k<<<55296, 256, 0, stream>>>(inprj, outw, wbin, wbout);           // 14.16M elems exactly
  input_proj_k<<<NTOK * D_MODEL / 256, 256, 0, stream>>>(x, inpw, inpb, h);

  for (int l = 0; l < 4; ++l) {
    rmsnorm_k<<<NTOK, 256, 0, stream>>>(h, lnw + l * D_MODEL, xn);
    gemm_bt<false><<<dim3(32, 24), 256, 0, stream>>>(xn, wbin + (size_t)l * 3072 * 768, xz, 3072, 768);
    conv_silu_k<<<NTOK * D_INNER / 256, 256, 0, stream>>>(xz, convw + l * D_INNER * 4, convb + l * D_INNER, xxa);
    xproj_k<<<dim3(64, XP_KSEG), 256, 0, stream>>>(xxa, xprjw + (size_t)l * 80 * D_INNER, dbcp);
    reduce_dbc_k<<<NTOK * 80 / 256, 256, 0, stream>>>(dbcp, dbc);
    dtproj_k<<<dim3(NTOK / 16, 6), 256, 0, stream>>>(dbc, dtw + (size_t)l * D_INNER * DT_RANK,
                                                     dtb + l * D_INNER, dlt);
    scan_p1_k<<<dim3(NCHUNK, 6, NB), 256, 0, stream>>>(dlt, xxa, dbc, alog + (size_t)l * D_INNER * 16, Pb, Sb);
    scan_p3_k<<<dim3(NCHUNK, 6, NB), 256, 0, stream>>>(dlt, xxa, dbc, alog + (size_t)l * D_INNER * 16,
                                                       Pb, Sb, xz, dskip + l * D_INNER, yg);
    gemm_bt<true><<<dim3(32, 6), 256, 0, stream>>>(yg, wbout + (size_t)l * 768 * 1536, h, 768, 1536);
  }

  final_k<<<NTOK, 256, 0, stream>>>(h, normw, headw, headb, out);
}

// Round 2
// 1069.240 us; speedup vs baseline: 1.1380x; 1.1380x over previous
//
#include <hip/hip_runtime.h>
#include <stdint.h>

// Problem constants (fixed by reference)
#define D_MODEL   768
#define D_INNER   1536
#define D_STATE   16
#define DT_RANK   48
#define NB        4
#define TSEQ      1024
#define NTOK      4096         // NB*TSEQ
#define EPS       1e-5f
#define CHUNK     32           // scan chunk length
#define NCHUNK    32           // TSEQ/CHUNK
#define XP_KSEG   8            // split-K segments for x_proj
#define XP_PAD    36           // padded LDS stride (floats) for x_proj tiles

typedef __bf16 bf16;
typedef __bf16 bf16x8 __attribute__((ext_vector_type(8)));
typedef float  floatx4 __attribute__((ext_vector_type(4)));

__device__ __forceinline__ float silu_f(float v)     { return v / (1.f + __expf(-v)); }
__device__ __forceinline__ float softplus_f(float v) { return v > 20.f ? v : __logf(1.f + __expf(v)); }

// async global->LDS, 16B per lane; LDS dest is wave-uniform base + lane*16
__device__ __forceinline__ void async_ld16(const void* g, void* l) {
  __builtin_amdgcn_global_load_lds((__attribute__((address_space(1))) uint32_t*)g,
                                   (__attribute__((address_space(3))) uint32_t*)l, 16, 0, 0);
}

// ---------------------------------------------------------------- prep: fp32 -> bf16 weights
__global__ __launch_bounds__(256) void prep_k(const float* __restrict__ win, const float* __restrict__ wout,
                                              bf16* __restrict__ bin, bf16* __restrict__ bout) {
  const int i = blockIdx.x * 256 + threadIdx.x;     // grid covers exactly NIN+NOUT
  const int NIN = 4 * 3072 * 768;
  if (i < NIN) bin[i] = (bf16)win[i];
  else         bout[i - NIN] = (bf16)wout[i - NIN];
}

// ---------------------------------------------------------------- input projection (K=12)
__global__ __launch_bounds__(256) void input_proj_k(const float* __restrict__ x, const float* __restrict__ w,
                                                    const float* __restrict__ bvec, float* __restrict__ h) {
  const int idx = blockIdx.x * 256 + threadIdx.x;   // NTOK*768
  const int d = idx % D_MODEL;
  const int t = idx / D_MODEL;
  float acc = bvec[d];
  #pragma unroll
  for (int f = 0; f < 12; ++f) acc = fmaf(x[t * 12 + f], w[d * 12 + f], acc);
  h[idx] = acc;
}

// ---------------------------------------------------------------- rmsnorm -> bf16
__global__ __launch_bounds__(256) void rmsnorm_k(const float* __restrict__ h, const float* __restrict__ lnw,
                                                 bf16* __restrict__ xn) {
  const int t = blockIdx.x;
  const float* __restrict__ hr = h + (size_t)t * D_MODEL;
  float v[3];
  float ss = 0.f;
  #pragma unroll
  for (int i = 0; i < 3; ++i) { v[i] = hr[threadIdx.x + i * 256]; ss = fmaf(v[i], v[i], ss); }
  #pragma unroll
  for (int o = 32; o > 0; o >>= 1) ss += __shfl_down(ss, o, 64);
  __shared__ float red[4];
  if ((threadIdx.x & 63) == 0) red[threadIdx.x >> 6] = ss;
  __syncthreads();
  const float tot = red[0] + red[1] + red[2] + red[3];
  const float rs = rsqrtf(tot / (float)D_MODEL + EPS);
  #pragma unroll
  for (int i = 0; i < 3; ++i) {
    const int d = threadIdx.x + i * 256;
    xn[(size_t)t * D_MODEL + d] = (bf16)(v[i] * rs * lnw[d]);
  }
}

// ---------------------------------------------------------------- bf16 MFMA GEMM: C[4096,N] (+)= A[4096,K] @ B[N,K]^T
// m97 structure: 128x128 tile, BK=32, 4 waves of 64x64, global_load_lds width16.
// MODE: 0 = overwrite, 2 = atomicAdd (split-K; blockIdx.z selects K-segment of kLen)
template <int MODE>
__global__ __launch_bounds__(256) void gemm_bt(const bf16* __restrict__ A, const bf16* __restrict__ B,
                                               float* __restrict__ C, const int N, const int K, const int kLen) {
  alignas(16) __shared__ bf16 As[128 * 32];
  alignas(16) __shared__ bf16 Bs[128 * 32];
  const int tid = threadIdx.x;
  const int lane = tid & 63;
  const int wid = tid >> 6;
  const int wm = wid & 1, wn = wid >> 1;
  const int m0 = blockIdx.x * 128, n0 = blockIdx.y * 128;
  const int kOff = blockIdx.z * kLen;

  floatx4 acc[4][4];
  #pragma unroll
  for (int i = 0; i < 4; ++i)
    #pragma unroll
    for (int j = 0; j < 4; ++j) acc[i][j] = (floatx4){0.f, 0.f, 0.f, 0.f};

  const int srow = lane >> 2;          // staging: row within 16-row segment
  const int skp  = (lane & 3) * 8;     // staging: k offset (8 bf16 = 16B)
  const int fr = lane & 15;            // fragment row
  const int fk = (lane >> 4) * 8;      // fragment k

  for (int k0 = 0; k0 < kLen; k0 += 32) {
    __syncthreads();                   // all waves done reading LDS from prev iter
    #pragma unroll
    for (int i = 0; i < 2; ++i) {
      const int seg = wid * 2 + i;     // 8 segments x 1KB per matrix
      const int row = seg * 16 + srow;
      async_ld16(A + (size_t)(m0 + row) * K + kOff + k0 + skp, (char*)As + seg * 1024);
      async_ld16(B + (size_t)(n0 + row) * K + kOff + k0 + skp, (char*)Bs + seg * 1024);
    }
    __syncthreads();                   // compiler drains vmcnt(0) before barrier
    bf16x8 a[4], b[4];
    #pragma unroll
    for (int t = 0; t < 4; ++t) {
      a[t] = *(const bf16x8*)&As[(wm * 64 + t * 16 + fr) * 32 + fk];
      b[t] = *(const bf16x8*)&Bs[(wn * 64 + t * 16 + fr) * 32 + fk];
    }
    #pragma unroll
    for (int i = 0; i < 4; ++i)
      #pragma unroll
      for (int j = 0; j < 4; ++j)
        acc[i][j] = __builtin_amdgcn_mfma_f32_16x16x32_bf16(a[i], b[j], acc[i][j], 0, 0, 0);
  }

  const int quad = lane >> 4, col = lane & 15;
  #pragma unroll
  for (int i = 0; i < 4; ++i)
    #pragma unroll
    for (int j = 0; j < 4; ++j) {
      const int gm0 = m0 + wm * 64 + i * 16 + quad * 4;
      const int gn  = n0 + wn * 64 + j * 16 + col;
      #pragma unroll
      for (int r = 0; r < 4; ++r) {
        const size_t off = (size_t)(gm0 + r) * N + gn;
        const float v = acc[i][j][r];
        if (MODE == 0) C[off] = v;
        else           atomicAdd(&C[off], v);
      }
    }
}

// ---------------------------------------------------------------- causal depthwise conv4 + silu
__global__ __launch_bounds__(256) void conv_silu_k(const float* __restrict__ xz, const float* __restrict__ cw,
                                                   const float* __restrict__ cb, float* __restrict__ xx) {
  const int idx = blockIdx.x * 256 + threadIdx.x;   // NTOK*1536
  const int d = idx % D_INNER;
  const int bt = idx / D_INNER;
  const int t = bt & (TSEQ - 1);
  float acc = cb[d];
  #pragma unroll
  for (int j = 0; j < 4; ++j) {
    const int tt = t - 3 + j;
    if (tt >= 0) acc = fmaf(xz[(size_t)(bt - 3 + j) * (2 * D_INNER) + d], cw[d * 4 + j], acc);
  }
  xx[idx] = silu_f(acc);
}

// ---------------------------------------------------------------- x_proj (N=80, split-K fp32, LDS tiled)
__global__ __launch_bounds__(256) void xproj_k(const float* __restrict__ xx, const float* __restrict__ xpw,
                                               float* __restrict__ dbcp) {
  alignas(16) __shared__ float xs[64 * XP_PAD];
  alignas(16) __shared__ float wsd[80 * XP_PAD];
  const int tid = threadIdx.x;
  const int m0 = blockIdx.x * 64;
  const int kbase = blockIdx.y * (D_INNER / XP_KSEG);   // 192 per segment
  const int mg = tid & 15, ng = tid >> 4;               // 4 tokens x 5 outputs per thread
  float acc[4][5];
  #pragma unroll
  for (int i = 0; i < 4; ++i)
    #pragma unroll
    for (int j = 0; j < 5; ++j) acc[i][j] = 0.f;

  for (int k0 = 0; k0 < D_INNER / XP_KSEG; k0 += 32) {
    __syncthreads();
    #pragma unroll
    for (int i = 0; i < 2; ++i) {                       // 64x32 activation tile
      const int li = tid + i * 256;
      const int row = li >> 3, c4 = (li & 7) * 4;
      *(float4*)&xs[row * XP_PAD + c4] = *(const float4*)&xx[(size_t)(m0 + row) * D_INNER + kbase + k0 + c4];
    }
    #pragma unroll
    for (int i = 0; i < 3; ++i) {                       // 80x32 weight tile
      const int li = tid + i * 256;
      if (li < 640) {
        const int row = li >> 3, c4 = (li & 7) * 4;
        *(float4*)&wsd[row * XP_PAD + c4] = *(const float4*)&xpw[(size_t)row * D_INNER + kbase + k0 + c4];
      }
    }
    __syncthreads();
    #pragma unroll
    for (int q = 0; q < 8; ++q) {
      float4 wv[5];
      #pragma unroll
      for (int j = 0; j < 5; ++j) wv[j] = *(const float4*)&wsd[(ng * 5 + j) * XP_PAD + q * 4];
      #pragma unroll
      for (int i = 0; i < 4; ++i) {
        const float4 xv = *(const float4*)&xs[(mg * 4 + i) * XP_PAD + q * 4];
        #pragma unroll
        for (int j = 0; j < 5; ++j) {
          acc[i][j] = fmaf(xv.x, wv[j].x, acc[i][j]);
          acc[i][j] = fmaf(xv.y, wv[j].y, acc[i][j]);
          acc[i][j] = fmaf(xv.z, wv[j].z, acc[i][j]);
          acc[i][j] = fmaf(xv.w, wv[j].w, acc[i][j]);
        }
      }
    }
  }
  #pragma unroll
  for (int i = 0; i < 4; ++i)
    #pragma unroll
    for (int j = 0; j < 5; ++j)
      dbcp[((size_t)blockIdx.y * NTOK + m0 + mg * 4 + i) * 80 + ng * 5 + j] = acc[i][j];
}

__global__ __launch_bounds__(256) void reduce_dbc_k(const float* __restrict__ dbcp, float* __restrict__ dbc) {
  const int idx = blockIdx.x * 256 + threadIdx.x;       // NTOK*80
  float s = 0.f;
  #pragma unroll
  for (int k = 0; k < XP_KSEG; ++k) s += dbcp[(size_t)k * NTOK * 80 + idx];
  dbc[idx] = s;
}

// ---------------------------------------------------------------- dt_proj + softplus (K=48 in registers)
__global__ __launch_bounds__(256) void dtproj_k(const float* __restrict__ dbc, const float* __restrict__ dtw,
                                                const float* __restrict__ dtb, float* __restrict__ delta) {
  const int d = blockIdx.y * 256 + threadIdx.x;
  const int t0 = blockIdx.x * 16;
  float w[DT_RANK];
  #pragma unroll
  for (int k = 0; k < DT_RANK; k += 4) {
    const float4 t4 = *(const float4*)&dtw[(size_t)d * DT_RANK + k];
    w[k] = t4.x; w[k + 1] = t4.y; w[k + 2] = t4.z; w[k + 3] = t4.w;
  }
  const float bias = dtb[d];
  for (int m = 0; m < 16; ++m) {
    const float* __restrict__ db = dbc + (size_t)(t0 + m) * 80;   // lane-uniform -> s_load
    float acc = bias;
    #pragma unroll
    for (int k = 0; k < DT_RANK; ++k) acc = fmaf(db[k], w[k], acc);
    delta[(size_t)(t0 + m) * D_INNER + d] = softplus_f(acc);
  }
}

// ---------------------------------------------------------------- chunked selective scan, phase 1:
// per chunk: P[n] = prod a_t[n], S[n] = local state from zero init
__global__ __launch_bounds__(256) void scan_p1_k(const float* __restrict__ delta, const float* __restrict__ xx,
                                                 const float* __restrict__ dbc, const float* __restrict__ Alog,
                                                 float* __restrict__ P, float* __restrict__ S) {
  const int c = blockIdx.x;
  const int d = blockIdx.y * 256 + threadIdx.x;
  const int b = blockIdx.z;
  float A[16], Sv[16], Pv[16];
  #pragma unroll
  for (int n = 0; n < 16; ++n) {
    A[n] = -__expf(Alog[(size_t)d * 16 + n]);
    Sv[n] = 0.f; Pv[n] = 1.f;
  }
  const int bt0 = b * TSEQ + c * CHUNK;
  for (int tt = 0; tt < CHUNK; ++tt) {
    const size_t bt = bt0 + tt;
    const float du  = delta[bt * D_INNER + d];
    const float xv  = xx[bt * D_INNER + d];
    const float dux = du * xv;
    const float* __restrict__ Bp = dbc + bt * 80 + DT_RANK;       // lane-uniform -> s_load
    #pragma unroll
    for (int n = 0; n < 16; ++n) {
      const float e = __expf(du * A[n]);
      Sv[n] = fmaf(e, Sv[n], dux * Bp[n]);
      Pv[n] *= e;
    }
  }
  const size_t base = ((size_t)(b * NCHUNK + c) * 16) * D_INNER + d;
  #pragma unroll
  for (int n = 0; n < 16; ++n) {
    P[base + (size_t)n * D_INNER] = Pv[n];
    S[base + (size_t)n * D_INNER] = Sv[n];
  }
}

// ---------------------------------------------------------------- phase 2: sequential chunk-prefix fold
// one thread per (b, n, d); walks 32 chunks: Hin[c] = H; H = P[c]*H + S[c]
__global__ __launch_bounds__(256) void scan_fold_k(const float* __restrict__ P, const float* __restrict__ S,
                                                   float* __restrict__ Hin) {
  const int idx = blockIdx.x * 256 + threadIdx.x;       // NB*16*D_INNER = 98304
  const int d = idx % D_INNER;
  const int bn = idx / D_INNER;
  const int n = bn & 15;
  const int b = bn >> 4;
  float H = 0.f;
  #pragma unroll 4
  for (int c = 0; c < NCHUNK; ++c) {
    const size_t off = ((size_t)((b * NCHUNK + c) * 16 + n)) * D_INNER + d;
    Hin[off] = H;
    H = fmaf(P[off], H, S[off]);
  }
}

// phase 3: load incoming state, replay chunk, fuse D-skip + silu(z) gate, emit bf16
__global__ __launch_bounds__(256) void scan_p3_k(const float* __restrict__ delta, const float* __restrict__ xx,
                                                 const float* __restrict__ dbc, const float* __restrict__ Alog,
                                                 const float* __restrict__ Hin,
                                                 const float* __restrict__ xz, const float* __restrict__ Dsk,
                                                 bf16* __restrict__ yg) {
  const int c = blockIdx.x;
  const int d = blockIdx.y * 256 + threadIdx.x;
  const int b = blockIdx.z;
  const size_t hbase = ((size_t)(b * NCHUNK + c) * 16) * D_INNER + d;
  float A[16], H[16];
  #pragma unroll
  for (int n = 0; n < 16; ++n) {
    A[n] = -__expf(Alog[(size_t)d * 16 + n]);
    H[n] = Hin[hbase + (size_t)n * D_INNER];
  }
  const float dsk = Dsk[d];
  const int bt0 = b * TSEQ + c * CHUNK;
  for (int tt = 0; tt < CHUNK; ++tt) {
    const size_t bt = bt0 + tt;
    const float du  = delta[bt * D_INNER + d];
    const float xv  = xx[bt * D_INNER + d];
    const float dux = du * xv;
    const float* __restrict__ Bp = dbc + bt * 80 + DT_RANK;
    const float* __restrict__ Cp = Bp + 16;
    float y = 0.f;
    #pragma unroll
    for (int n = 0; n < 16; ++n) {
      const float e = __expf(du * A[n]);
      H[n] = fmaf(e, H[n], dux * Bp[n]);
      y = fmaf(H[n], Cp[n], y);
    }
    const float z = xz[bt * (2 * D_INNER) + D_INNER + d];
    yg[bt * D_INNER + d] = (bf16)((y + dsk * xv) * silu_f(z));
  }
}

// ---------------------------------------------------------------- final rmsnorm + head dot
__global__ __launch_bounds__(256) void final_k(const float* __restrict__ h, const float* __restrict__ nw,
                                               const float* __restrict__ hw, const float* __restrict__ hb,
                                               float* __restrict__ out) {
  const int t = blockIdx.x;
  const float* __restrict__ hr = h + (size_t)t * D_MODEL;
  float ss = 0.f, dt_ = 0.f;
  #pragma unroll
  for (int i = 0; i < 3; ++i) {
    const int d = threadIdx.x + i * 256;
    const float v = hr[d];
    ss  = fmaf(v, v, ss);
    dt_ = fmaf(v, nw[d] * hw[d], dt_);
  }
  #pragma unroll
  for (int o = 32; o > 0; o >>= 1) { ss += __shfl_down(ss, o, 64); dt_ += __shfl_down(dt_, o, 64); }
  __shared__ float r0[4], r1[4];
  if ((threadIdx.x & 63) == 0) { r0[threadIdx.x >> 6] = ss; r1[threadIdx.x >> 6] = dt_; }
  __syncthreads();
  if (threadIdx.x == 0) {
    const float sst = r0[0] + r0[1] + r0[2] + r0[3];
    const float dtt = r1[0] + r1[1] + r1[2] + r1[3];
    out[t] = dtt * rsqrtf(sst / (float)D_MODEL + EPS) + hb[0];
  }
}

// ---------------------------------------------------------------- host orchestration
extern "C" void kernel_launch(void* const* d_in, const int* in_sizes, int n_in,
                              void* d_out, int out_size, void* d_ws, size_t ws_size,
                              hipStream_t stream) {
  (void)in_sizes; (void)n_in; (void)out_size; (void)ws_size;
  const float* x     = (const float*)d_in[0];
  const float* inpw  = (const float*)d_in[1];
  const float* inpb  = (const float*)d_in[2];
  const float* inprj = (const float*)d_in[3];
  const float* convw = (const float*)d_in[4];
  const float* convb = (const float*)d_in[5];
  const float* xprjw = (const float*)d_in[6];
  const float* dtw   = (const float*)d_in[7];
  const float* dtb   = (const float*)d_in[8];
  const float* alog  = (const float*)d_in[9];
  const float* dskip = (const float*)d_in[10];
  const float* outw  = (const float*)d_in[11];
  const float* lnw   = (const float*)d_in[12];
  const float* normw = (const float*)d_in[13];
  const float* headw = (const float*)d_in[14];
  const float* headb = (const float*)d_in[15];
  float* out = (float*)d_out;

  // workspace layout
  char* p = (char*)d_ws;
  auto take = [&](size_t bytes) { char* q = p; p += (bytes + 255) & ~(size_t)255; return q; };
  bf16*  wbin  = (bf16*) take((size_t)4 * 3072 * 768 * 2);
  bf16*  wbout = (bf16*) take((size_t)4 * 768 * 1536 * 2);
  float* h     = (float*)take((size_t)NTOK * D_MODEL * 4);
  bf16*  xn    = (bf16*) take((size_t)NTOK * D_MODEL * 2);
  float* xz    = (float*)take((size_t)NTOK * 2 * D_INNER * 4);
  float* xxa   = (float*)take((size_t)NTOK * D_INNER * 4);
  float* dbcp  = (float*)take((size_t)XP_KSEG * NTOK * 80 * 4);
  float* dbc   = (float*)take((size_t)NTOK * 80 * 4);
  float* dlt   = (float*)take((size_t)NTOK * D_INNER * 4);
  float* Pb    = (float*)take((size_t)NB * NCHUNK * 16 * D_INNER * 4);
  float* Sb    = (float*)take((size_t)NB * NCHUNK * 16 * D_INNER * 4);
  float* Hin   = (float*)take((size_t)NB * NCHUNK * 16 * D_INNER * 4);
  bf16*  yg    = (bf16*) take((size_t)NTOK * D_INNER * 2);

  prep_k<<<55296, 256, 0, stream>>>(inprj, outw, wbin, wbout);           // 14.16M elems exactly
  input_proj_k<<<NTOK * D_MODEL / 256, 256, 0, stream>>>(x, inpw, inpb, h);

  for (int l = 0; l < 4; ++l) {
    rmsnorm_k<<<NTOK, 256, 0, stream>>>(h, lnw + l * D_MODEL, xn);
    gemm_bt<0><<<dim3(32, 24, 1), 256, 0, stream>>>(xn, wbin + (size_t)l * 3072 * 768, xz, 3072, 768, 768);
    conv_silu_k<<<NTOK * D_INNER / 256, 256, 0, stream>>>(xz, convw + l * D_INNER * 4, convb + l * D_INNER, xxa);
    xproj_k<<<dim3(64, XP_KSEG), 256, 0, stream>>>(xxa, xprjw + (size_t)l * 80 * D_INNER, dbcp);
    reduce_dbc_k<<<NTOK * 80 / 256, 256, 0, stream>>>(dbcp, dbc);
    dtproj_k<<<dim3(NTOK / 16, 6), 256, 0, stream>>>(dbc, dtw + (size_t)l * D_INNER * DT_RANK,
                                                     dtb + l * D_INNER, dlt);
    scan_p1_k<<<dim3(NCHUNK, 6, NB), 256, 0, stream>>>(dlt, xxa, dbc, alog + (size_t)l * D_INNER * 16, Pb, Sb);
    scan_fold_k<<<NB * 16 * D_INNER / 256, 256, 0, stream>>>(Pb, Sb, Hin);
    scan_p3_k<<<dim3(NCHUNK, 6, NB), 256, 0, stream>>>(dlt, xxa, dbc, alog + (size_t)l * D_INNER * 16,
                                                       Hin, xz, dskip + l * D_INNER, yg);
    gemm_bt<2><<<dim3(32, 6, 2), 256, 0, stream>>>(yg, wbout + (size_t)l * 768 * 1536, h, 768, 1536, 768);
  }

  final_k<<<NTOK, 256, 0, stream>>>(h, normw, headw, headb, out);
}

// Round 3
// 986.327 us; speedup vs baseline: 1.2336x; 1.0841x over previous
//
#include <hip/hip_runtime.h>
#include <stdint.h>

// Problem constants (fixed by reference)
#define D_MODEL   768
#define D_INNER   1536
#define D_STATE   16
#define DT_RANK   48
#define NB        4
#define TSEQ      1024
#define NTOK      4096         // NB*TSEQ
#define EPS       1e-5f
#define CHUNK     32           // scan chunk length
#define NCHUNK    32           // TSEQ/CHUNK
#define XP_N      128          // x_proj output padded 80 -> 128 for MFMA tile

typedef __bf16 bf16;
typedef __bf16 bf16x8 __attribute__((ext_vector_type(8)));
typedef float  floatx4 __attribute__((ext_vector_type(4)));

__device__ __forceinline__ float silu_f(float v)     { return v / (1.f + __expf(-v)); }
__device__ __forceinline__ float softplus_f(float v) { return v > 20.f ? v : __logf(1.f + __expf(v)); }

// async global->LDS, 16B per lane; LDS dest is wave-uniform base + lane*16
__device__ __forceinline__ void async_ld16(const void* g, void* l) {
  __builtin_amdgcn_global_load_lds((__attribute__((address_space(1))) uint32_t*)g,
                                   (__attribute__((address_space(3))) uint32_t*)l, 16, 0, 0);
}

// ---------------------------------------------------------------- prep: fp32 -> bf16 weights
__global__ __launch_bounds__(256) void prep_k(const float* __restrict__ win, const float* __restrict__ wout,
                                              bf16* __restrict__ bin, bf16* __restrict__ bout) {
  const int i = blockIdx.x * 256 + threadIdx.x;     // grid covers exactly NIN+NOUT
  const int NIN = 4 * 3072 * 768;
  if (i < NIN) bin[i] = (bf16)win[i];
  else         bout[i - NIN] = (bf16)wout[i - NIN];
}

// x_proj weight: [4][80][1536] fp32 -> [4][128][1536] bf16, rows 80..127 zero
__global__ __launch_bounds__(256) void prep_xp_k(const float* __restrict__ w, bf16* __restrict__ wb) {
  const int i = blockIdx.x * 256 + threadIdx.x;     // 4*128*1536
  const int k = i % 1536;
  const int r = (i / 1536) % XP_N;
  const int l = i / (1536 * XP_N);
  wb[i] = (r < 80) ? (bf16)w[((size_t)l * 80 + r) * 1536 + k] : (bf16)0.f;
}

// ---------------------------------------------------------------- input projection (K=12)
__global__ __launch_bounds__(256) void input_proj_k(const float* __restrict__ x, const float* __restrict__ w,
                                                    const float* __restrict__ bvec, float* __restrict__ h) {
  const int idx = blockIdx.x * 256 + threadIdx.x;   // NTOK*768
  const int d = idx % D_MODEL;
  const int t = idx / D_MODEL;
  float acc = bvec[d];
  #pragma unroll
  for (int f = 0; f < 12; ++f) acc = fmaf(x[t * 12 + f], w[d * 12 + f], acc);
  h[idx] = acc;
}

// ---------------------------------------------------------------- rmsnorm -> bf16
__global__ __launch_bounds__(256) void rmsnorm_k(const float* __restrict__ h, const float* __restrict__ lnw,
                                                 bf16* __restrict__ xn) {
  const int t = blockIdx.x;
  const float* __restrict__ hr = h + (size_t)t * D_MODEL;
  float v[3];
  float ss = 0.f;
  #pragma unroll
  for (int i = 0; i < 3; ++i) { v[i] = hr[threadIdx.x + i * 256]; ss = fmaf(v[i], v[i], ss); }
  #pragma unroll
  for (int o = 32; o > 0; o >>= 1) ss += __shfl_down(ss, o, 64);
  __shared__ float red[4];
  if ((threadIdx.x & 63) == 0) red[threadIdx.x >> 6] = ss;
  __syncthreads();
  const float tot = red[0] + red[1] + red[2] + red[3];
  const float rs = rsqrtf(tot / (float)D_MODEL + EPS);
  #pragma unroll
  for (int i = 0; i < 3; ++i) {
    const int d = threadIdx.x + i * 256;
    xn[(size_t)t * D_MODEL + d] = (bf16)(v[i] * rs * lnw[d]);
  }
}

// ---------------------------------------------------------------- bf16 MFMA GEMM: C[4096,N] (+)= A[4096,K] @ B[N,K]^T
// m97 structure: 128x128 tile, BK=32, 4 waves of 64x64, global_load_lds width16.
// MODE: 0 = overwrite, 2 = atomicAdd (split-K; blockIdx.z selects K-segment of kLen)
template <int MODE>
__global__ __launch_bounds__(256) void gemm_bt(const bf16* __restrict__ A, const bf16* __restrict__ B,
                                               float* __restrict__ C, const int N, const int K, const int kLen) {
  alignas(16) __shared__ bf16 As[128 * 32];
  alignas(16) __shared__ bf16 Bs[128 * 32];
  const int tid = threadIdx.x;
  const int lane = tid & 63;
  const int wid = tid >> 6;
  const int wm = wid & 1, wn = wid >> 1;
  const int m0 = blockIdx.x * 128, n0 = blockIdx.y * 128;
  const int kOff = blockIdx.z * kLen;

  floatx4 acc[4][4];
  #pragma unroll
  for (int i = 0; i < 4; ++i)
    #pragma unroll
    for (int j = 0; j < 4; ++j) acc[i][j] = (floatx4){0.f, 0.f, 0.f, 0.f};

  const int srow = lane >> 2;          // staging: row within 16-row segment
  const int skp  = (lane & 3) * 8;     // staging: k offset (8 bf16 = 16B)
  const int fr = lane & 15;            // fragment row
  const int fk = (lane >> 4) * 8;      // fragment k

  for (int k0 = 0; k0 < kLen; k0 += 32) {
    __syncthreads();                   // all waves done reading LDS from prev iter
    #pragma unroll
    for (int i = 0; i < 2; ++i) {
      const int seg = wid * 2 + i;     // 8 segments x 1KB per matrix
      const int row = seg * 16 + srow;
      async_ld16(A + (size_t)(m0 + row) * K + kOff + k0 + skp, (char*)As + seg * 1024);
      async_ld16(B + (size_t)(n0 + row) * K + kOff + k0 + skp, (char*)Bs + seg * 1024);
    }
    __syncthreads();                   // compiler drains vmcnt(0) before barrier
    bf16x8 a[4], b[4];
    #pragma unroll
    for (int t = 0; t < 4; ++t) {
      a[t] = *(const bf16x8*)&As[(wm * 64 + t * 16 + fr) * 32 + fk];
      b[t] = *(const bf16x8*)&Bs[(wn * 64 + t * 16 + fr) * 32 + fk];
    }
    #pragma unroll
    for (int i = 0; i < 4; ++i)
      #pragma unroll
      for (int j = 0; j < 4; ++j)
        acc[i][j] = __builtin_amdgcn_mfma_f32_16x16x32_bf16(a[i], b[j], acc[i][j], 0, 0, 0);
  }

  const int quad = lane >> 4, col = lane & 15;
  #pragma unroll
  for (int i = 0; i < 4; ++i)
    #pragma unroll
    for (int j = 0; j < 4; ++j) {
      const int gm0 = m0 + wm * 64 + i * 16 + quad * 4;
      const int gn  = n0 + wn * 64 + j * 16 + col;
      #pragma unroll
      for (int r = 0; r < 4; ++r) {
        const size_t off = (size_t)(gm0 + r) * N + gn;
        const float v = acc[i][j][r];
        if (MODE == 0) C[off] = v;
        else           atomicAdd(&C[off], v);
      }
    }
}

// ---------------------------------------------------------------- causal depthwise conv4 + silu (fp32 + bf16 outs)
__global__ __launch_bounds__(256) void conv_silu_k(const float* __restrict__ xz, const float* __restrict__ cw,
                                                   const float* __restrict__ cb, float* __restrict__ xx,
                                                   bf16* __restrict__ xxb) {
  const int idx = blockIdx.x * 256 + threadIdx.x;   // NTOK*1536
  const int d = idx % D_INNER;
  const int bt = idx / D_INNER;
  const int t = bt & (TSEQ - 1);
  float acc = cb[d];
  #pragma unroll
  for (int j = 0; j < 4; ++j) {
    const int tt = t - 3 + j;
    if (tt >= 0) acc = fmaf(xz[(size_t)(bt - 3 + j) * (2 * D_INNER) + d], cw[d * 4 + j], acc);
  }
  const float s = silu_f(acc);
  xx[idx] = s;
  xxb[idx] = (bf16)s;
}

// ---------------------------------------------------------------- dt_proj + softplus (K=48 in registers)
__global__ __launch_bounds__(256) void dtproj_k(const float* __restrict__ dbc, const float* __restrict__ dtw,
                                                const float* __restrict__ dtb, float* __restrict__ delta) {
  const int d = blockIdx.y * 256 + threadIdx.x;
  const int t0 = blockIdx.x * 16;
  float w[DT_RANK];
  #pragma unroll
  for (int k = 0; k < DT_RANK; k += 4) {
    const float4 t4 = *(const float4*)&dtw[(size_t)d * DT_RANK + k];
    w[k] = t4.x; w[k + 1] = t4.y; w[k + 2] = t4.z; w[k + 3] = t4.w;
  }
  const float bias = dtb[d];
  for (int m = 0; m < 16; ++m) {
    const float* __restrict__ db = dbc + (size_t)(t0 + m) * XP_N;   // lane-uniform -> s_load
    float acc = bias;
    #pragma unroll
    for (int k = 0; k < DT_RANK; ++k) acc = fmaf(db[k], w[k], acc);
    delta[(size_t)(t0 + m) * D_INNER + d] = softplus_f(acc);
  }
}

// ---------------------------------------------------------------- chunked selective scan, phase 1:
// per chunk: P[n] = prod a_t[n], S[n] = local state from zero init
__global__ __launch_bounds__(256) void scan_p1_k(const float* __restrict__ delta, const float* __restrict__ xx,
                                                 const float* __restrict__ dbc, const float* __restrict__ Alog,
                                                 float* __restrict__ P, float* __restrict__ S) {
  const int c = blockIdx.x;
  const int d = blockIdx.y * 256 + threadIdx.x;
  const int b = blockIdx.z;
  float A[16], Sv[16], Pv[16];
  #pragma unroll
  for (int n = 0; n < 16; ++n) {
    A[n] = -__expf(Alog[(size_t)d * 16 + n]);
    Sv[n] = 0.f; Pv[n] = 1.f;
  }
  const int bt0 = b * TSEQ + c * CHUNK;
  for (int tt = 0; tt < CHUNK; ++tt) {
    const size_t bt = bt0 + tt;
    const float du  = delta[bt * D_INNER + d];
    const float xv  = xx[bt * D_INNER + d];
    const float dux = du * xv;
    const float* __restrict__ Bp = dbc + bt * XP_N + DT_RANK;     // lane-uniform -> s_load
    #pragma unroll
    for (int n = 0; n < 16; ++n) {
      const float e = __expf(du * A[n]);
      Sv[n] = fmaf(e, Sv[n], dux * Bp[n]);
      Pv[n] *= e;
    }
  }
  const size_t base = ((size_t)(b * NCHUNK + c) * 16) * D_INNER + d;
  #pragma unroll
  for (int n = 0; n < 16; ++n) {
    P[base + (size_t)n * D_INNER] = Pv[n];
    S[base + (size_t)n * D_INNER] = Sv[n];
  }
}

// ---------------------------------------------------------------- phase 2: sequential chunk-prefix fold
// one thread per (b, n, d); walks 32 chunks: Hin[c] = H; H = P[c]*H + S[c]
__global__ __launch_bounds__(256) void scan_fold_k(const float* __restrict__ P, const float* __restrict__ S,
                                                   float* __restrict__ Hin) {
  const int idx = blockIdx.x * 256 + threadIdx.x;       // NB*16*D_INNER = 98304
  const int d = idx % D_INNER;
  const int bn = idx / D_INNER;
  const int n = bn & 15;
  const int b = bn >> 4;
  float H = 0.f;
  #pragma unroll 4
  for (int c = 0; c < NCHUNK; ++c) {
    const size_t off = ((size_t)((b * NCHUNK + c) * 16 + n)) * D_INNER + d;
    Hin[off] = H;
    H = fmaf(P[off], H, S[off]);
  }
}

// phase 3: load incoming state, replay chunk, fuse D-skip + silu(z) gate, emit bf16
__global__ __launch_bounds__(256) void scan_p3_k(const float* __restrict__ delta, const float* __restrict__ xx,
                                                 const float* __restrict__ dbc, const float* __restrict__ Alog,
                                                 const float* __restrict__ Hin,
                                                 const float* __restrict__ xz, const float* __restrict__ Dsk,
                                                 bf16* __restrict__ yg) {
  const int c = blockIdx.x;
  const int d = blockIdx.y * 256 + threadIdx.x;
  const int b = blockIdx.z;
  const size_t hbase = ((size_t)(b * NCHUNK + c) * 16) * D_INNER + d;
  float A[16], H[16];
  #pragma unroll
  for (int n = 0; n < 16; ++n) {
    A[n] = -__expf(Alog[(size_t)d * 16 + n]);
    H[n] = Hin[hbase + (size_t)n * D_INNER];
  }
  const float dsk = Dsk[d];
  const int bt0 = b * TSEQ + c * CHUNK;
  for (int tt = 0; tt < CHUNK; ++tt) {
    const size_t bt = bt0 + tt;
    const float du  = delta[bt * D_INNER + d];
    const float xv  = xx[bt * D_INNER + d];
    const float dux = du * xv;
    const float* __restrict__ Bp = dbc + bt * XP_N + DT_RANK;
    const float* __restrict__ Cp = Bp + 16;
    float y = 0.f;
    #pragma unroll
    for (int n = 0; n < 16; ++n) {
      const float e = __expf(du * A[n]);
      H[n] = fmaf(e, H[n], dux * Bp[n]);
      y = fmaf(H[n], Cp[n], y);
    }
    const float z = xz[bt * (2 * D_INNER) + D_INNER + d];
    yg[bt * D_INNER + d] = (bf16)((y + dsk * xv) * silu_f(z));
  }
}

// ---------------------------------------------------------------- final rmsnorm + head dot
__global__ __launch_bounds__(256) void final_k(const float* __restrict__ h, const float* __restrict__ nw,
                                               const float* __restrict__ hw, const float* __restrict__ hb,
                                               float* __restrict__ out) {
  const int t = blockIdx.x;
  const float* __restrict__ hr = h + (size_t)t * D_MODEL;
  float ss = 0.f, dt_ = 0.f;
  #pragma unroll
  for (int i = 0; i < 3; ++i) {
    const int d = threadIdx.x + i * 256;
    const float v = hr[d];
    ss  = fmaf(v, v, ss);
    dt_ = fmaf(v, nw[d] * hw[d], dt_);
  }
  #pragma unroll
  for (int o = 32; o > 0; o >>= 1) { ss += __shfl_down(ss, o, 64); dt_ += __shfl_down(dt_, o, 64); }
  __shared__ float r0[4], r1[4];
  if ((threadIdx.x & 63) == 0) { r0[threadIdx.x >> 6] = ss; r1[threadIdx.x >> 6] = dt_; }
  __syncthreads();
  if (threadIdx.x == 0) {
    const float sst = r0[0] + r0[1] + r0[2] + r0[3];
    const float dtt = r1[0] + r1[1] + r1[2] + r1[3];
    out[t] = dtt * rsqrtf(sst / (float)D_MODEL + EPS) + hb[0];
  }
}

// ---------------------------------------------------------------- host orchestration
extern "C" void kernel_launch(void* const* d_in, const int* in_sizes, int n_in,
                              void* d_out, int out_size, void* d_ws, size_t ws_size,
                              hipStream_t stream) {
  (void)in_sizes; (void)n_in; (void)out_size; (void)ws_size;
  const float* x     = (const float*)d_in[0];
  const float* inpw  = (const float*)d_in[1];
  const float* inpb  = (const float*)d_in[2];
  const float* inprj = (const float*)d_in[3];
  const float* convw = (const float*)d_in[4];
  const float* convb = (const float*)d_in[5];
  const float* xprjw = (const float*)d_in[6];
  const float* dtw   = (const float*)d_in[7];
  const float* dtb   = (const float*)d_in[8];
  const float* alog  = (const float*)d_in[9];
  const float* dskip = (const float*)d_in[10];
  const float* outw  = (const float*)d_in[11];
  const float* lnw   = (const float*)d_in[12];
  const float* normw = (const float*)d_in[13];
  const float* headw = (const float*)d_in[14];
  const float* headb = (const float*)d_in[15];
  float* out = (float*)d_out;

  // workspace layout
  char* p = (char*)d_ws;
  auto take = [&](size_t bytes) { char* q = p; p += (bytes + 255) & ~(size_t)255; return q; };
  bf16*  wbin  = (bf16*) take((size_t)4 * 3072 * 768 * 2);
  bf16*  wbout = (bf16*) take((size_t)4 * 768 * 1536 * 2);
  bf16*  wbxp  = (bf16*) take((size_t)4 * XP_N * 1536 * 2);
  float* h     = (float*)take((size_t)NTOK * D_MODEL * 4);
  bf16*  xn    = (bf16*) take((size_t)NTOK * D_MODEL * 2);
  float* xz    = (float*)take((size_t)NTOK * 2 * D_INNER * 4);
  float* xxa   = (float*)take((size_t)NTOK * D_INNER * 4);
  bf16*  xxb   = (bf16*) take((size_t)NTOK * D_INNER * 2);
  float* dbc   = (float*)take((size_t)NTOK * XP_N * 4);
  float* dlt   = (float*)take((size_t)NTOK * D_INNER * 4);
  float* Pb    = (float*)take((size_t)NB * NCHUNK * 16 * D_INNER * 4);
  float* Sb    = (float*)take((size_t)NB * NCHUNK * 16 * D_INNER * 4);
  float* Hin   = (float*)take((size_t)NB * NCHUNK * 16 * D_INNER * 4);
  bf16*  yg    = (bf16*) take((size_t)NTOK * D_INNER * 2);

  prep_k<<<55296, 256, 0, stream>>>(inprj, outw, wbin, wbout);           // 14.16M elems exactly
  prep_xp_k<<<4 * XP_N * 1536 / 256, 256, 0, stream>>>(xprjw, wbxp);
  input_proj_k<<<NTOK * D_MODEL / 256, 256, 0, stream>>>(x, inpw, inpb, h);

  for (int l = 0; l < 4; ++l) {
    rmsnorm_k<<<NTOK, 256, 0, stream>>>(h, lnw + l * D_MODEL, xn);
    gemm_bt<0><<<dim3(32, 24, 1), 256, 0, stream>>>(xn, wbin + (size_t)l * 3072 * 768, xz, 3072, 768, 768);
    conv_silu_k<<<NTOK * D_INNER / 256, 256, 0, stream>>>(xz, convw + l * D_INNER * 4, convb + l * D_INNER,
                                                          xxa, xxb);
    hipMemsetAsync(dbc, 0, (size_t)NTOK * XP_N * 4, stream);
    gemm_bt<2><<<dim3(32, 1, 4), 256, 0, stream>>>(xxb, wbxp + (size_t)l * XP_N * 1536, dbc, XP_N, 1536, 384);
    dtproj_k<<<dim3(NTOK / 16, 6), 256, 0, stream>>>(dbc, dtw + (size_t)l * D_INNER * DT_RANK,
                                                     dtb + l * D_INNER, dlt);
    scan_p1_k<<<dim3(NCHUNK, 6, NB), 256, 0, stream>>>(dlt, xxa, dbc, alog + (size_t)l * D_INNER * 16, Pb, Sb);
    scan_fold_k<<<NB * 16 * D_INNER / 256, 256, 0, stream>>>(Pb, Sb, Hin);
    scan_p3_k<<<dim3(NCHUNK, 6, NB), 256, 0, stream>>>(dlt, xxa, dbc, alog + (size_t)l * D_INNER * 16,
                                                       Hin, xz, dskip + l * D_INNER, yg);
    gemm_bt<2><<<dim3(32, 6, 2), 256, 0, stream>>>(yg, wbout + (size_t)l * 768 * 1536, h, 768, 1536, 768);
  }

  final_k<<<NTOK, 256, 0, stream>>>(h, normw, headw, headb, out);
}

// Round 4
// 968.877 us; speedup vs baseline: 1.2558x; 1.0180x over previous
//
#include <hip/hip_runtime.h>
#include <stdint.h>

// Problem constants (fixed by reference)
#define D_MODEL   768
#define D_INNER   1536
#define D_STATE   16
#define DT_RANK   48
#define NB        4
#define TSEQ      1024
#define NTOK      4096         // NB*TSEQ
#define EPS       1e-5f
#define CHUNK     32           // scan chunk length
#define NCHUNK    32           // TSEQ/CHUNK
#define XP_N      128          // x_proj output padded 80 -> 128 for MFMA tile

typedef __bf16 bf16;
typedef __bf16 bf16x8 __attribute__((ext_vector_type(8)));
typedef float  floatx4 __attribute__((ext_vector_type(4)));

__device__ __forceinline__ float silu_f(float v)     { return v / (1.f + __expf(-v)); }
__device__ __forceinline__ float softplus_f(float v) { return v > 20.f ? v : __logf(1.f + __expf(v)); }

// async global->LDS, 16B per lane; LDS dest is wave-uniform base + lane*16
__device__ __forceinline__ void async_ld16(const void* g, void* l) {
  __builtin_amdgcn_global_load_lds((__attribute__((address_space(1))) uint32_t*)g,
                                   (__attribute__((address_space(3))) uint32_t*)l, 16, 0, 0);
}

// ---------------------------------------------------------------- prep: fp32 -> bf16 weights
__global__ __launch_bounds__(256) void prep_k(const float* __restrict__ win, const float* __restrict__ wout,
                                              bf16* __restrict__ bin, bf16* __restrict__ bout) {
  const int i = blockIdx.x * 256 + threadIdx.x;     // grid covers exactly NIN+NOUT
  const int NIN = 4 * 3072 * 768;
  if (i < NIN) bin[i] = (bf16)win[i];
  else         bout[i - NIN] = (bf16)wout[i - NIN];
}

// x_proj weight: [4][80][1536] fp32 -> [4][128][1536] bf16, rows 80..127 zero
__global__ __launch_bounds__(256) void prep_xp_k(const float* __restrict__ w, bf16* __restrict__ wb) {
  const int i = blockIdx.x * 256 + threadIdx.x;     // 4*128*1536
  const int k = i % 1536;
  const int r = (i / 1536) % XP_N;
  const int l = i / (1536 * XP_N);
  wb[i] = (r < 80) ? (bf16)w[((size_t)l * 80 + r) * 1536 + k] : (bf16)0.f;
}

// ---------------------------------------------------------------- input projection (K=12)
__global__ __launch_bounds__(256) void input_proj_k(const float* __restrict__ x, const float* __restrict__ w,
                                                    const float* __restrict__ bvec, float* __restrict__ h) {
  const int idx = blockIdx.x * 256 + threadIdx.x;   // NTOK*768
  const int d = idx % D_MODEL;
  const int t = idx / D_MODEL;
  float acc = bvec[d];
  #pragma unroll
  for (int f = 0; f < 12; ++f) acc = fmaf(x[t * 12 + f], w[d * 12 + f], acc);
  h[idx] = acc;
}

// ---------------------------------------------------------------- rmsnorm -> bf16
__global__ __launch_bounds__(256) void rmsnorm_k(const float* __restrict__ h, const float* __restrict__ lnw,
                                                 bf16* __restrict__ xn) {
  const int t = blockIdx.x;
  const float* __restrict__ hr = h + (size_t)t * D_MODEL;
  float v[3];
  float ss = 0.f;
  #pragma unroll
  for (int i = 0; i < 3; ++i) { v[i] = hr[threadIdx.x + i * 256]; ss = fmaf(v[i], v[i], ss); }
  #pragma unroll
  for (int o = 32; o > 0; o >>= 1) ss += __shfl_down(ss, o, 64);
  __shared__ float red[4];
  if ((threadIdx.x & 63) == 0) red[threadIdx.x >> 6] = ss;
  __syncthreads();
  const float tot = red[0] + red[1] + red[2] + red[3];
  const float rs = rsqrtf(tot / (float)D_MODEL + EPS);
  #pragma unroll
  for (int i = 0; i < 3; ++i) {
    const int d = threadIdx.x + i * 256;
    xn[(size_t)t * D_MODEL + d] = (bf16)(v[i] * rs * lnw[d]);
  }
}

// ---------------------------------------------------------------- bf16 MFMA GEMM: C[4096,N] (+)= A[4096,K] @ B[N,K]^T
// m97 structure: 128x128 tile, BK=32, 4 waves of 64x64, global_load_lds width16.
// MODE: 0 = fp32 overwrite, 1 = bf16 overwrite, 2 = fp32 atomicAdd (split-K via blockIdx.z)
template <int MODE>
__global__ __launch_bounds__(256) void gemm_bt(const bf16* __restrict__ A, const bf16* __restrict__ B,
                                               void* __restrict__ Cv, const int N, const int K, const int kLen) {
  alignas(16) __shared__ bf16 As[128 * 32];
  alignas(16) __shared__ bf16 Bs[128 * 32];
  const int tid = threadIdx.x;
  const int lane = tid & 63;
  const int wid = tid >> 6;
  const int wm = wid & 1, wn = wid >> 1;
  const int m0 = blockIdx.x * 128, n0 = blockIdx.y * 128;
  const int kOff = blockIdx.z * kLen;

  floatx4 acc[4][4];
  #pragma unroll
  for (int i = 0; i < 4; ++i)
    #pragma unroll
    for (int j = 0; j < 4; ++j) acc[i][j] = (floatx4){0.f, 0.f, 0.f, 0.f};

  const int srow = lane >> 2;          // staging: row within 16-row segment
  const int skp  = (lane & 3) * 8;     // staging: k offset (8 bf16 = 16B)
  const int fr = lane & 15;            // fragment row
  const int fk = (lane >> 4) * 8;      // fragment k

  for (int k0 = 0; k0 < kLen; k0 += 32) {
    __syncthreads();                   // all waves done reading LDS from prev iter
    #pragma unroll
    for (int i = 0; i < 2; ++i) {
      const int seg = wid * 2 + i;     // 8 segments x 1KB per matrix
      const int row = seg * 16 + srow;
      async_ld16(A + (size_t)(m0 + row) * K + kOff + k0 + skp, (char*)As + seg * 1024);
      async_ld16(B + (size_t)(n0 + row) * K + kOff + k0 + skp, (char*)Bs + seg * 1024);
    }
    __syncthreads();                   // compiler drains vmcnt(0) before barrier
    bf16x8 a[4], b[4];
    #pragma unroll
    for (int t = 0; t < 4; ++t) {
      a[t] = *(const bf16x8*)&As[(wm * 64 + t * 16 + fr) * 32 + fk];
      b[t] = *(const bf16x8*)&Bs[(wn * 64 + t * 16 + fr) * 32 + fk];
    }
    #pragma unroll
    for (int i = 0; i < 4; ++i)
      #pragma unroll
      for (int j = 0; j < 4; ++j)
        acc[i][j] = __builtin_amdgcn_mfma_f32_16x16x32_bf16(a[i], b[j], acc[i][j], 0, 0, 0);
  }

  const int quad = lane >> 4, col = lane & 15;
  #pragma unroll
  for (int i = 0; i < 4; ++i)
    #pragma unroll
    for (int j = 0; j < 4; ++j) {
      const int gm0 = m0 + wm * 64 + i * 16 + quad * 4;
      const int gn  = n0 + wn * 64 + j * 16 + col;
      #pragma unroll
      for (int r = 0; r < 4; ++r) {
        const size_t off = (size_t)(gm0 + r) * N + gn;
        const float v = acc[i][j][r];
        if (MODE == 0)      ((float*)Cv)[off] = v;
        else if (MODE == 1) ((bf16*)Cv)[off] = (bf16)v;
        else                atomicAdd(&((float*)Cv)[off], v);
      }
    }
}

// ---------------------------------------------------------------- causal depthwise conv4 + silu (bf16 in/out)
__global__ __launch_bounds__(256) void conv_silu_k(const bf16* __restrict__ xz, const float* __restrict__ cw,
                                                   const float* __restrict__ cb, bf16* __restrict__ xxb) {
  const int idx = blockIdx.x * 256 + threadIdx.x;   // NTOK*1536
  const int d = idx % D_INNER;
  const int bt = idx / D_INNER;
  const int t = bt & (TSEQ - 1);
  float acc = cb[d];
  #pragma unroll
  for (int j = 0; j < 4; ++j) {
    const int tt = t - 3 + j;
    if (tt >= 0) acc = fmaf((float)xz[(size_t)(bt - 3 + j) * (2 * D_INNER) + d], cw[d * 4 + j], acc);
  }
  xxb[idx] = (bf16)silu_f(acc);
}

// ---------------------------------------------------------------- chunked selective scan, phase 1 (+fused dt_proj):
// per chunk: P[n] = prod a_t[n], S[n] = local state from zero init
__global__ __launch_bounds__(256) void scan_p1_k(const bf16* __restrict__ xxb, const float* __restrict__ dbc,
                                                 const float* __restrict__ dtw, const float* __restrict__ dtb,
                                                 const float* __restrict__ Alog,
                                                 float* __restrict__ P, float* __restrict__ S) {
  const int c = blockIdx.x;
  const int d = blockIdx.y * 256 + threadIdx.x;
  const int b = blockIdx.z;
  float w[DT_RANK];
  #pragma unroll
  for (int k = 0; k < DT_RANK; k += 4) {
    const float4 t4 = *(const float4*)&dtw[(size_t)d * DT_RANK + k];
    w[k] = t4.x; w[k + 1] = t4.y; w[k + 2] = t4.z; w[k + 3] = t4.w;
  }
  const float bias = dtb[d];
  float A[16], Sv[16], Pv[16];
  #pragma unroll
  for (int n = 0; n < 16; ++n) {
    A[n] = -__expf(Alog[(size_t)d * 16 + n]);
    Sv[n] = 0.f; Pv[n] = 1.f;
  }
  const int bt0 = b * TSEQ + c * CHUNK;
  for (int tt = 0; tt < CHUNK; ++tt) {
    const size_t bt = bt0 + tt;
    const float* __restrict__ db = dbc + bt * XP_N;               // lane-uniform -> s_load
    float dacc = bias;
    #pragma unroll
    for (int k = 0; k < DT_RANK; ++k) dacc = fmaf(db[k], w[k], dacc);
    const float du  = softplus_f(dacc);
    const float xv  = (float)xxb[bt * D_INNER + d];
    const float dux = du * xv;
    const float* __restrict__ Bp = db + DT_RANK;
    #pragma unroll
    for (int n = 0; n < 16; ++n) {
      const float e = __expf(du * A[n]);
      Sv[n] = fmaf(e, Sv[n], dux * Bp[n]);
      Pv[n] *= e;
    }
  }
  const size_t base = ((size_t)(b * NCHUNK + c) * 16) * D_INNER + d;
  #pragma unroll
  for (int n = 0; n < 16; ++n) {
    P[base + (size_t)n * D_INNER] = Pv[n];
    S[base + (size_t)n * D_INNER] = Sv[n];
  }
}

// ---------------------------------------------------------------- phase 2: sequential chunk-prefix fold
// one thread per (b, n, d); walks 32 chunks: Hin <- S in place: S[c] = H; H = P[c]*H + S_old[c]
__global__ __launch_bounds__(256) void scan_fold_k(const float* __restrict__ P, float* __restrict__ S) {
  const int idx = blockIdx.x * 256 + threadIdx.x;       // NB*16*D_INNER = 98304
  const int d = idx % D_INNER;
  const int bn = idx / D_INNER;
  const int n = bn & 15;
  const int b = bn >> 4;
  float H = 0.f;
  #pragma unroll 4
  for (int c = 0; c < NCHUNK; ++c) {
    const size_t off = ((size_t)((b * NCHUNK + c) * 16 + n)) * D_INNER + d;
    const float Pv = P[off], Sv = S[off];
    S[off] = H;                       // S becomes Hin (incoming state for chunk c)
    H = fmaf(Pv, H, Sv);
  }
}

// phase 3 (+fused dt_proj): load incoming state, replay chunk, fuse D-skip + silu(z) gate, emit bf16
__global__ __launch_bounds__(256) void scan_p3_k(const bf16* __restrict__ xxb, const float* __restrict__ dbc,
                                                 const float* __restrict__ dtw, const float* __restrict__ dtb,
                                                 const float* __restrict__ Alog,
                                                 const float* __restrict__ Hin,
                                                 const bf16* __restrict__ xz, const float* __restrict__ Dsk,
                                                 bf16* __restrict__ yg) {
  const int c = blockIdx.x;
  const int d = blockIdx.y * 256 + threadIdx.x;
  const int b = blockIdx.z;
  float w[DT_RANK];
  #pragma unroll
  for (int k = 0; k < DT_RANK; k += 4) {
    const float4 t4 = *(const float4*)&dtw[(size_t)d * DT_RANK + k];
    w[k] = t4.x; w[k + 1] = t4.y; w[k + 2] = t4.z; w[k + 3] = t4.w;
  }
  const float bias = dtb[d];
  const size_t hbase = ((size_t)(b * NCHUNK + c) * 16) * D_INNER + d;
  float A[16], H[16];
  #pragma unroll
  for (int n = 0; n < 16; ++n) {
    A[n] = -__expf(Alog[(size_t)d * 16 + n]);
    H[n] = Hin[hbase + (size_t)n * D_INNER];
  }
  const float dsk = Dsk[d];
  const int bt0 = b * TSEQ + c * CHUNK;
  for (int tt = 0; tt < CHUNK; ++tt) {
    const size_t bt = bt0 + tt;
    const float* __restrict__ db = dbc + bt * XP_N;               // lane-uniform -> s_load
    float dacc = bias;
    #pragma unroll
    for (int k = 0; k < DT_RANK; ++k) dacc = fmaf(db[k], w[k], dacc);
    const float du  = softplus_f(dacc);
    const float xv  = (float)xxb[bt * D_INNER + d];
    const float dux = du * xv;
    const float* __restrict__ Bp = db + DT_RANK;
    const float* __restrict__ Cp = db + DT_RANK + 16;
    float y = 0.f;
    #pragma unroll
    for (int n = 0; n < 16; ++n) {
      const float e = __expf(du * A[n]);
      H[n] = fmaf(e, H[n], dux * Bp[n]);
      y = fmaf(H[n], Cp[n], y);
    }
    const float z = (float)xz[bt * (2 * D_INNER) + D_INNER + d];
    yg[bt * D_INNER + d] = (bf16)((y + dsk * xv) * silu_f(z));
  }
}

// ---------------------------------------------------------------- final rmsnorm + head dot
__global__ __launch_bounds__(256) void final_k(const float* __restrict__ h, const float* __restrict__ nw,
                                               const float* __restrict__ hw, const float* __restrict__ hb,
                                               float* __restrict__ out) {
  const int t = blockIdx.x;
  const float* __restrict__ hr = h + (size_t)t * D_MODEL;
  float ss = 0.f, dt_ = 0.f;
  #pragma unroll
  for (int i = 0; i < 3; ++i) {
    const int d = threadIdx.x + i * 256;
    const float v = hr[d];
    ss  = fmaf(v, v, ss);
    dt_ = fmaf(v, nw[d] * hw[d], dt_);
  }
  #pragma unroll
  for (int o = 32; o > 0; o >>= 1) { ss += __shfl_down(ss, o, 64); dt_ += __shfl_down(dt_, o, 64); }
  __shared__ float r0[4], r1[4];
  if ((threadIdx.x & 63) == 0) { r0[threadIdx.x >> 6] = ss; r1[threadIdx.x >> 6] = dt_; }
  __syncthreads();
  if (threadIdx.x == 0) {
    const float sst = r0[0] + r0[1] + r0[2] + r0[3];
    const float dtt = r1[0] + r1[1] + r1[2] + r1[3];
    out[t] = dtt * rsqrtf(sst / (float)D_MODEL + EPS) + hb[0];
  }
}

// ---------------------------------------------------------------- host orchestration
extern "C" void kernel_launch(void* const* d_in, const int* in_sizes, int n_in,
                              void* d_out, int out_size, void* d_ws, size_t ws_size,
                              hipStream_t stream) {
  (void)in_sizes; (void)n_in; (void)out_size; (void)ws_size;
  const float* x     = (const float*)d_in[0];
  const float* inpw  = (const float*)d_in[1];
  const float* inpb  = (const float*)d_in[2];
  const float* inprj = (const float*)d_in[3];
  const float* convw = (const float*)d_in[4];
  const float* convb = (const float*)d_in[5];
  const float* xprjw = (const float*)d_in[6];
  const float* dtw   = (const float*)d_in[7];
  const float* dtb   = (const float*)d_in[8];
  const float* alog  = (const float*)d_in[9];
  const float* dskip = (const float*)d_in[10];
  const float* outw  = (const float*)d_in[11];
  const float* lnw   = (const float*)d_in[12];
  const float* normw = (const float*)d_in[13];
  const float* headw = (const float*)d_in[14];
  const float* headb = (const float*)d_in[15];
  float* out = (float*)d_out;

  // workspace layout (~126 MB; poison cost scales with ws bytes)
  char* p = (char*)d_ws;
  auto take = [&](size_t bytes) { char* q = p; p += (bytes + 255) & ~(size_t)255; return q; };
  bf16*  wbin  = (bf16*) take((size_t)4 * 3072 * 768 * 2);
  bf16*  wbout = (bf16*) take((size_t)4 * 768 * 1536 * 2);
  bf16*  wbxp  = (bf16*) take((size_t)4 * XP_N * 1536 * 2);
  float* h     = (float*)take((size_t)NTOK * D_MODEL * 4);
  bf16*  xn    = (bf16*) take((size_t)NTOK * D_MODEL * 2);
  bf16*  xzb   = (bf16*) take((size_t)NTOK * 2 * D_INNER * 2);
  bf16*  xxb   = (bf16*) take((size_t)NTOK * D_INNER * 2);
  float* dbc   = (float*)take((size_t)NTOK * XP_N * 4);
  float* Pb    = (float*)take((size_t)NB * NCHUNK * 16 * D_INNER * 4);
  float* Sb    = (float*)take((size_t)NB * NCHUNK * 16 * D_INNER * 4);   // becomes Hin in fold
  bf16*  yg    = (bf16*) take((size_t)NTOK * D_INNER * 2);

  prep_k<<<55296, 256, 0, stream>>>(inprj, outw, wbin, wbout);           // 14.16M elems exactly
  prep_xp_k<<<4 * XP_N * 1536 / 256, 256, 0, stream>>>(xprjw, wbxp);
  input_proj_k<<<NTOK * D_MODEL / 256, 256, 0, stream>>>(x, inpw, inpb, h);

  for (int l = 0; l < 4; ++l) {
    rmsnorm_k<<<NTOK, 256, 0, stream>>>(h, lnw + l * D_MODEL, xn);
    gemm_bt<1><<<dim3(32, 24, 1), 256, 0, stream>>>(xn, wbin + (size_t)l * 3072 * 768, xzb, 3072, 768, 768);
    conv_silu_k<<<NTOK * D_INNER / 256, 256, 0, stream>>>(xzb, convw + l * D_INNER * 4, convb + l * D_INNER, xxb);
    hipMemsetAsync(dbc, 0, (size_t)NTOK * XP_N * 4, stream);
    gemm_bt<2><<<dim3(32, 1, 4), 256, 0, stream>>>(xxb, wbxp + (size_t)l * XP_N * 1536, dbc, XP_N, 1536, 384);
    scan_p1_k<<<dim3(NCHUNK, 6, NB), 256, 0, stream>>>(xxb, dbc, dtw + (size_t)l * D_INNER * DT_RANK,
                                                       dtb + l * D_INNER, alog + (size_t)l * D_INNER * 16, Pb, Sb);
    scan_fold_k<<<NB * 16 * D_INNER / 256, 256, 0, stream>>>(Pb, Sb);
    scan_p3_k<<<dim3(NCHUNK, 6, NB), 256, 0, stream>>>(xxb, dbc, dtw + (size_t)l * D_INNER * DT_RANK,
                                                       dtb + l * D_INNER, alog + (size_t)l * D_INNER * 16,
                                                       Sb, xzb, dskip + l * D_INNER, yg);
    gemm_bt<2><<<dim3(32, 6, 2), 256, 0, stream>>>(yg, wbout + (size_t)l * 768 * 1536, h, 768, 1536, 768);
  }

  final_k<<<NTOK, 256, 0, stream>>>(h, normw, headw, headb, out);
}

// Round 5
// 867.436 us; speedup vs baseline: 1.4027x; 1.1169x over previous
//
#include <hip/hip_runtime.h>
#include <stdint.h>

// Problem constants (fixed by reference)
#define D_MODEL   768
#define D_INNER   1536
#define D_STATE   16
#define DT_RANK   48
#define NB        4
#define TSEQ      1024
#define NTOK      4096         // NB*TSEQ
#define EPS       1e-5f
#define CHUNK     32           // scan chunk length
#define NCHUNK    32           // TSEQ/CHUNK
#define XP_N      128          // x_proj output padded 80 -> 128 for MFMA tile

typedef __bf16 bf16;
typedef __bf16 bf16x8 __attribute__((ext_vector_type(8)));
typedef float  floatx4 __attribute__((ext_vector_type(4)));

__device__ __forceinline__ float silu_f(float v)     { return v / (1.f + __expf(-v)); }
__device__ __forceinline__ float softplus_f(float v) { return v > 20.f ? v : __logf(1.f + __expf(v)); }

// async global->LDS, 16B per lane; LDS dest is wave-uniform base + lane*16
__device__ __forceinline__ void async_ld16(const void* g, void* l) {
  __builtin_amdgcn_global_load_lds((__attribute__((address_space(1))) uint32_t*)g,
                                   (__attribute__((address_space(3))) uint32_t*)l, 16, 0, 0);
}

// ---------------------------------------------------------------- prep: fp32 -> bf16 weights
__global__ __launch_bounds__(256) void prep_k(const float* __restrict__ win, const float* __restrict__ wout,
                                              bf16* __restrict__ bin, bf16* __restrict__ bout) {
  const int i = blockIdx.x * 256 + threadIdx.x;     // grid covers exactly NIN+NOUT
  const int NIN = 4 * 3072 * 768;
  if (i < NIN) bin[i] = (bf16)win[i];
  else         bout[i - NIN] = (bf16)wout[i - NIN];
}

// x_proj weight: [4][80][1536] fp32 -> [4][128][1536] bf16, rows 80..127 zero
__global__ __launch_bounds__(256) void prep_xp_k(const float* __restrict__ w, bf16* __restrict__ wb) {
  const int i = blockIdx.x * 256 + threadIdx.x;     // 4*128*1536
  const int k = i % 1536;
  const int r = (i / 1536) % XP_N;
  const int l = i / (1536 * XP_N);
  wb[i] = (r < 80) ? (bf16)w[((size_t)l * 80 + r) * 1536 + k] : (bf16)0.f;
}

// ---------------------------------------------------------------- input projection (K=12)
__global__ __launch_bounds__(256) void input_proj_k(const float* __restrict__ x, const float* __restrict__ w,
                                                    const float* __restrict__ bvec, float* __restrict__ h) {
  const int idx = blockIdx.x * 256 + threadIdx.x;   // NTOK*768
  const int d = idx % D_MODEL;
  const int t = idx / D_MODEL;
  float acc = bvec[d];
  #pragma unroll
  for (int f = 0; f < 12; ++f) acc = fmaf(x[t * 12 + f], w[d * 12 + f], acc);
  h[idx] = acc;
}

// ---------------------------------------------------------------- rmsnorm -> bf16
__global__ __launch_bounds__(256) void rmsnorm_k(const float* __restrict__ h, const float* __restrict__ lnw,
                                                 bf16* __restrict__ xn) {
  const int t = blockIdx.x;
  const float* __restrict__ hr = h + (size_t)t * D_MODEL;
  float v[3];
  float ss = 0.f;
  #pragma unroll
  for (int i = 0; i < 3; ++i) { v[i] = hr[threadIdx.x + i * 256]; ss = fmaf(v[i], v[i], ss); }
  #pragma unroll
  for (int o = 32; o > 0; o >>= 1) ss += __shfl_down(ss, o, 64);
  __shared__ float red[4];
  if ((threadIdx.x & 63) == 0) red[threadIdx.x >> 6] = ss;
  __syncthreads();
  const float tot = red[0] + red[1] + red[2] + red[3];
  const float rs = rsqrtf(tot / (float)D_MODEL + EPS);
  #pragma unroll
  for (int i = 0; i < 3; ++i) {
    const int d = threadIdx.x + i * 256;
    xn[(size_t)t * D_MODEL + d] = (bf16)(v[i] * rs * lnw[d]);
  }
}

// ---------------------------------------------------------------- bf16 MFMA GEMM: C[4096,N] (+)= A[4096,K] @ B[N,K]^T
// m97 structure: 128x128 tile, BK=32, 4 waves of 64x64, global_load_lds width16.
// MODE: 0 = fp32 overwrite, 1 = bf16 overwrite, 2 = fp32 atomicAdd (split-K via blockIdx.z)
template <int MODE>
__global__ __launch_bounds__(256) void gemm_bt(const bf16* __restrict__ A, const bf16* __restrict__ B,
                                               void* __restrict__ Cv, const int N, const int K, const int kLen) {
  alignas(16) __shared__ bf16 As[128 * 32];
  alignas(16) __shared__ bf16 Bs[128 * 32];
  const int tid = threadIdx.x;
  const int lane = tid & 63;
  const int wid = tid >> 6;
  const int wm = wid & 1, wn = wid >> 1;
  const int m0 = blockIdx.x * 128, n0 = blockIdx.y * 128;
  const int kOff = blockIdx.z * kLen;

  floatx4 acc[4][4];
  #pragma unroll
  for (int i = 0; i < 4; ++i)
    #pragma unroll
    for (int j = 0; j < 4; ++j) acc[i][j] = (floatx4){0.f, 0.f, 0.f, 0.f};

  const int srow = lane >> 2;          // staging: row within 16-row segment
  const int skp  = (lane & 3) * 8;     // staging: k offset (8 bf16 = 16B)
  const int fr = lane & 15;            // fragment row
  const int fk = (lane >> 4) * 8;      // fragment k

  for (int k0 = 0; k0 < kLen; k0 += 32) {
    __syncthreads();                   // all waves done reading LDS from prev iter
    #pragma unroll
    for (int i = 0; i < 2; ++i) {
      const int seg = wid * 2 + i;     // 8 segments x 1KB per matrix
      const int row = seg * 16 + srow;
      async_ld16(A + (size_t)(m0 + row) * K + kOff + k0 + skp, (char*)As + seg * 1024);
      async_ld16(B + (size_t)(n0 + row) * K + kOff + k0 + skp, (char*)Bs + seg * 1024);
    }
    __syncthreads();                   // compiler drains vmcnt(0) before barrier
    bf16x8 a[4], b[4];
    #pragma unroll
    for (int t = 0; t < 4; ++t) {
      a[t] = *(const bf16x8*)&As[(wm * 64 + t * 16 + fr) * 32 + fk];
      b[t] = *(const bf16x8*)&Bs[(wn * 64 + t * 16 + fr) * 32 + fk];
    }
    #pragma unroll
    for (int i = 0; i < 4; ++i)
      #pragma unroll
      for (int j = 0; j < 4; ++j)
        acc[i][j] = __builtin_amdgcn_mfma_f32_16x16x32_bf16(a[i], b[j], acc[i][j], 0, 0, 0);
  }

  const int quad = lane >> 4, col = lane & 15;
  #pragma unroll
  for (int i = 0; i < 4; ++i)
    #pragma unroll
    for (int j = 0; j < 4; ++j) {
      const int gm0 = m0 + wm * 64 + i * 16 + quad * 4;
      const int gn  = n0 + wn * 64 + j * 16 + col;
      #pragma unroll
      for (int r = 0; r < 4; ++r) {
        const size_t off = (size_t)(gm0 + r) * N + gn;
        const float v = acc[i][j][r];
        if (MODE == 0)      ((float*)Cv)[off] = v;
        else if (MODE == 1) ((bf16*)Cv)[off] = (bf16)v;
        else                atomicAdd(&((float*)Cv)[off], v);
      }
    }
}

// ---------------------------------------------------------------- causal depthwise conv4 + silu (bf16 in/out)
__global__ __launch_bounds__(256) void conv_silu_k(const bf16* __restrict__ xz, const float* __restrict__ cw,
                                                   const float* __restrict__ cb, bf16* __restrict__ xxb) {
  const int idx = blockIdx.x * 256 + threadIdx.x;   // NTOK*1536
  const int d = idx % D_INNER;
  const int bt = idx / D_INNER;
  const int t = bt & (TSEQ - 1);
  float acc = cb[d];
  #pragma unroll
  for (int j = 0; j < 4; ++j) {
    const int tt = t - 3 + j;
    if (tt >= 0) acc = fmaf((float)xz[(size_t)(bt - 3 + j) * (2 * D_INNER) + d], cw[d * 4 + j], acc);
  }
  xxb[idx] = (bf16)silu_f(acc);
}

// ---------------------------------------------------------------- chunked selective scan, phase 1 (+fused dt_proj):
// per chunk: su = sum du_t, S[n] = local state from zero init; also stores delta for p3.
// Fast path exploits A_log = log(1..16) => A_n = -(n+1): e_n = r^(n+1), r = exp(-du).
__global__ __launch_bounds__(256) void scan_p1_k(const bf16* __restrict__ xxb, const float* __restrict__ dbc,
                                                 const float* __restrict__ dtw, const float* __restrict__ dtb,
                                                 const float* __restrict__ Alog,
                                                 float* __restrict__ S, float* __restrict__ su,
                                                 float* __restrict__ delta) {
  const int c = blockIdx.x;
  const int d = blockIdx.y * 256 + threadIdx.x;
  const int b = blockIdx.z;
  float w[DT_RANK];
  #pragma unroll
  for (int k = 0; k < DT_RANK; k += 4) {
    const float4 t4 = *(const float4*)&dtw[(size_t)d * DT_RANK + k];
    w[k] = t4.x; w[k + 1] = t4.y; w[k + 2] = t4.z; w[k + 3] = t4.w;
  }
  const float bias = dtb[d];
  float A[16], Sv[16];
  bool fast = true;
  #pragma unroll
  for (int n = 0; n < 16; ++n) {
    A[n] = -__expf(Alog[(size_t)d * 16 + n]);
    fast = fast && (__builtin_fabsf(A[n] + (float)(n + 1)) < 1e-3f);
    Sv[n] = 0.f;
  }
  float sus = 0.f;
  const int bt0 = b * TSEQ + c * CHUNK;
  if (fast) {
    for (int tt = 0; tt < CHUNK; ++tt) {
      const size_t bt = bt0 + tt;
      const float* __restrict__ db = dbc + bt * XP_N;             // lane-uniform -> s_load
      float dacc = bias;
      #pragma unroll
      for (int k = 0; k < DT_RANK; ++k) dacc = fmaf(db[k], w[k], dacc);
      const float du = softplus_f(dacc);
      delta[bt * D_INNER + d] = du;
      sus += du;
      const float xv  = (float)xxb[bt * D_INNER + d];
      const float dux = du * xv;
      const float* __restrict__ Bp = db + DT_RANK;
      const float r = __expf(-du);
      float e = r;
      #pragma unroll
      for (int n = 0; n < 16; ++n) {
        Sv[n] = fmaf(e, Sv[n], dux * Bp[n]);
        e *= r;
      }
    }
  } else {
    for (int tt = 0; tt < CHUNK; ++tt) {
      const size_t bt = bt0 + tt;
      const float* __restrict__ db = dbc + bt * XP_N;
      float dacc = bias;
      #pragma unroll
      for (int k = 0; k < DT_RANK; ++k) dacc = fmaf(db[k], w[k], dacc);
      const float du = softplus_f(dacc);
      delta[bt * D_INNER + d] = du;
      sus += du;
      const float xv  = (float)xxb[bt * D_INNER + d];
      const float dux = du * xv;
      const float* __restrict__ Bp = db + DT_RANK;
      #pragma unroll
      for (int n = 0; n < 16; ++n)
        Sv[n] = fmaf(__expf(du * A[n]), Sv[n], dux * Bp[n]);
    }
  }
  const size_t base = ((size_t)(b * NCHUNK + c) * 16) * D_INNER + d;
  #pragma unroll
  for (int n = 0; n < 16; ++n) S[base + (size_t)n * D_INNER] = Sv[n];
  su[(size_t)(b * NCHUNK + c) * D_INNER + d] = sus;
}

// ---------------------------------------------------------------- phase 2: sequential chunk-prefix fold
// one thread per (b, n, d); P_c = exp(A_n * su_c) (math identity); S <- Hin in place.
__global__ __launch_bounds__(256) void scan_fold_k(const float* __restrict__ Alog, const float* __restrict__ su,
                                                   float* __restrict__ S) {
  const int idx = blockIdx.x * 256 + threadIdx.x;       // NB*16*D_INNER = 98304
  const int d = idx % D_INNER;
  const int bn = idx / D_INNER;
  const int n = bn & 15;
  const int b = bn >> 4;
  const float A = -__expf(Alog[(size_t)d * 16 + n]);
  float H = 0.f;
  #pragma unroll 4
  for (int c = 0; c < NCHUNK; ++c) {
    const size_t off = ((size_t)((b * NCHUNK + c) * 16 + n)) * D_INNER + d;
    const float Pv = __expf(A * su[(size_t)(b * NCHUNK + c) * D_INNER + d]);
    const float Sv = S[off];
    S[off] = H;                       // S becomes Hin (incoming state for chunk c)
    H = fmaf(Pv, H, Sv);
  }
}

// phase 3: load incoming state + precomputed delta, replay chunk, fuse D-skip + silu(z) gate, emit bf16
__global__ __launch_bounds__(256) void scan_p3_k(const bf16* __restrict__ xxb, const float* __restrict__ dbc,
                                                 const float* __restrict__ delta, const float* __restrict__ Alog,
                                                 const float* __restrict__ Hin,
                                                 const bf16* __restrict__ xz, const float* __restrict__ Dsk,
                                                 bf16* __restrict__ yg) {
  const int c = blockIdx.x;
  const int d = blockIdx.y * 256 + threadIdx.x;
  const int b = blockIdx.z;
  const size_t hbase = ((size_t)(b * NCHUNK + c) * 16) * D_INNER + d;
  float A[16], H[16];
  bool fast = true;
  #pragma unroll
  for (int n = 0; n < 16; ++n) {
    A[n] = -__expf(Alog[(size_t)d * 16 + n]);
    fast = fast && (__builtin_fabsf(A[n] + (float)(n + 1)) < 1e-3f);
    H[n] = Hin[hbase + (size_t)n * D_INNER];
  }
  const float dsk = Dsk[d];
  const int bt0 = b * TSEQ + c * CHUNK;
  if (fast) {
    for (int tt = 0; tt < CHUNK; ++tt) {
      const size_t bt = bt0 + tt;
      const float du  = delta[bt * D_INNER + d];
      const float xv  = (float)xxb[bt * D_INNER + d];
      const float dux = du * xv;
      const float* __restrict__ db = dbc + bt * XP_N;             // lane-uniform -> s_load
      const float* __restrict__ Bp = db + DT_RANK;
      const float* __restrict__ Cp = db + DT_RANK + 16;
      const float r = __expf(-du);
      float e = r, y = 0.f;
      #pragma unroll
      for (int n = 0; n < 16; ++n) {
        H[n] = fmaf(e, H[n], dux * Bp[n]);
        y = fmaf(H[n], Cp[n], y);
        e *= r;
      }
      const float z = (float)xz[bt * (2 * D_INNER) + D_INNER + d];
      yg[bt * D_INNER + d] = (bf16)((y + dsk * xv) * silu_f(z));
    }
  } else {
    for (int tt = 0; tt < CHUNK; ++tt) {
      const size_t bt = bt0 + tt;
      const float du  = delta[bt * D_INNER + d];
      const float xv  = (float)xxb[bt * D_INNER + d];
      const float dux = du * xv;
      const float* __restrict__ db = dbc + bt * XP_N;
      const float* __restrict__ Bp = db + DT_RANK;
      const float* __restrict__ Cp = db + DT_RANK + 16;
      float y = 0.f;
      #pragma unroll
      for (int n = 0; n < 16; ++n) {
        H[n] = fmaf(__expf(du * A[n]), H[n], dux * Bp[n]);
        y = fmaf(H[n], Cp[n], y);
      }
      const float z = (float)xz[bt * (2 * D_INNER) + D_INNER + d];
      yg[bt * D_INNER + d] = (bf16)((y + dsk * xv) * silu_f(z));
    }
  }
}

// ---------------------------------------------------------------- final rmsnorm + head dot
__global__ __launch_bounds__(256) void final_k(const float* __restrict__ h, const float* __restrict__ nw,
                                               const float* __restrict__ hw, const float* __restrict__ hb,
                                               float* __restrict__ out) {
  const int t = blockIdx.x;
  const float* __restrict__ hr = h + (size_t)t * D_MODEL;
  float ss = 0.f, dt_ = 0.f;
  #pragma unroll
  for (int i = 0; i < 3; ++i) {
    const int d = threadIdx.x + i * 256;
    const float v = hr[d];
    ss  = fmaf(v, v, ss);
    dt_ = fmaf(v, nw[d] * hw[d], dt_);
  }
  #pragma unroll
  for (int o = 32; o > 0; o >>= 1) { ss += __shfl_down(ss, o, 64); dt_ += __shfl_down(dt_, o, 64); }
  __shared__ float r0[4], r1[4];
  if ((threadIdx.x & 63) == 0) { r0[threadIdx.x >> 6] = ss; r1[threadIdx.x >> 6] = dt_; }
  __syncthreads();
  if (threadIdx.x == 0) {
    const float sst = r0[0] + r0[1] + r0[2] + r0[3];
    const float dtt = r1[0] + r1[1] + r1[2] + r1[3];
    out[t] = dtt * rsqrtf(sst / (float)D_MODEL + EPS) + hb[0];
  }
}

// ---------------------------------------------------------------- host orchestration
extern "C" void kernel_launch(void* const* d_in, const int* in_sizes, int n_in,
                              void* d_out, int out_size, void* d_ws, size_t ws_size,
                              hipStream_t stream) {
  (void)in_sizes; (void)n_in; (void)out_size; (void)ws_size;
  const float* x     = (const float*)d_in[0];
  const float* inpw  = (const float*)d_in[1];
  const float* inpb  = (const float*)d_in[2];
  const float* inprj = (const float*)d_in[3];
  const float* convw = (const float*)d_in[4];
  const float* convb = (const float*)d_in[5];
  const float* xprjw = (const float*)d_in[6];
  const float* dtw   = (const float*)d_in[7];
  const float* dtb   = (const float*)d_in[8];
  const float* alog  = (const float*)d_in[9];
  const float* dskip = (const float*)d_in[10];
  const float* outw  = (const float*)d_in[11];
  const float* lnw   = (const float*)d_in[12];
  const float* normw = (const float*)d_in[13];
  const float* headw = (const float*)d_in[14];
  const float* headb = (const float*)d_in[15];
  float* out = (float*)d_out;

  // workspace layout (~127 MB; poison cost scales with ws bytes)
  char* p = (char*)d_ws;
  auto take = [&](size_t bytes) { char* q = p; p += (bytes + 255) & ~(size_t)255; return q; };
  bf16*  wbin  = (bf16*) take((size_t)4 * 3072 * 768 * 2);
  bf16*  wbout = (bf16*) take((size_t)4 * 768 * 1536 * 2);
  bf16*  wbxp  = (bf16*) take((size_t)4 * XP_N * 1536 * 2);
  float* h     = (float*)take((size_t)NTOK * D_MODEL * 4);
  bf16*  xn    = (bf16*) take((size_t)NTOK * D_MODEL * 2);
  bf16*  xzb   = (bf16*) take((size_t)NTOK * 2 * D_INNER * 2);
  bf16*  xxb   = (bf16*) take((size_t)NTOK * D_INNER * 2);
  float* dbc   = (float*)take((size_t)NTOK * XP_N * 4);
  float* dlt   = (float*)take((size_t)NTOK * D_INNER * 4);
  float* Sb    = (float*)take((size_t)NB * NCHUNK * 16 * D_INNER * 4);   // becomes Hin in fold
  float* su    = (float*)take((size_t)NB * NCHUNK * D_INNER * 4);
  bf16*  yg    = (bf16*) take((size_t)NTOK * D_INNER * 2);

  prep_k<<<55296, 256, 0, stream>>>(inprj, outw, wbin, wbout);           // 14.16M elems exactly
  prep_xp_k<<<4 * XP_N * 1536 / 256, 256, 0, stream>>>(xprjw, wbxp);
  input_proj_k<<<NTOK * D_MODEL / 256, 256, 0, stream>>>(x, inpw, inpb, h);

  for (int l = 0; l < 4; ++l) {
    rmsnorm_k<<<NTOK, 256, 0, stream>>>(h, lnw + l * D_MODEL, xn);
    gemm_bt<1><<<dim3(32, 24, 1), 256, 0, stream>>>(xn, wbin + (size_t)l * 3072 * 768, xzb, 3072, 768, 768);
    conv_silu_k<<<NTOK * D_INNER / 256, 256, 0, stream>>>(xzb, convw + l * D_INNER * 4, convb + l * D_INNER, xxb);
    hipMemsetAsync(dbc, 0, (size_t)NTOK * XP_N * 4, stream);
    gemm_bt<2><<<dim3(32, 1, 4), 256, 0, stream>>>(xxb, wbxp + (size_t)l * XP_N * 1536, dbc, XP_N, 1536, 384);
    scan_p1_k<<<dim3(NCHUNK, 6, NB), 256, 0, stream>>>(xxb, dbc, dtw + (size_t)l * D_INNER * DT_RANK,
                                                       dtb + l * D_INNER, alog + (size_t)l * D_INNER * 16,
                                                       Sb, su, dlt);
    scan_fold_k<<<NB * 16 * D_INNER / 256, 256, 0, stream>>>(alog + (size_t)l * D_INNER * 16, su, Sb);
    scan_p3_k<<<dim3(NCHUNK, 6, NB), 256, 0, stream>>>(xxb, dbc, dlt, alog + (size_t)l * D_INNER * 16,
                                                       Sb, xzb, dskip + l * D_INNER, yg);
    gemm_bt<2><<<dim3(32, 6, 2), 256, 0, stream>>>(yg, wbout + (size_t)l * 768 * 1536, h, 768, 1536, 768);
  }

  final_k<<<NTOK, 256, 0, stream>>>(h, normw, headw, headb, out);
}